// Round 5
// baseline (2253.033 us; speedup 1.0000x reference)
//
#include <hip/hip_runtime.h>
#include <hip/hip_bf16.h>

#define NN 20000
#define NE 320000
#define NL 12
#define BN_C 0.9999950000374997f

typedef __hip_bfloat16 bf16;

__device__ __forceinline__ float b2f(bf16 v){ return __bfloat162float(v); }
__device__ __forceinline__ bf16  f2b(float v){ return __float2bfloat16(v); }
__device__ __forceinline__ int finitef(float x){ return (x==x) && fabsf(x) < 1e30f; }

// dtype-dispatched input load / output store. F=1: float32 wire, F=0: bf16 wire.
__device__ __forceinline__ float ldin(const void* p, int i, int F){
  return F ? ((const float*)p)[i] : b2f(((const bf16*)p)[i]);
}
__device__ __forceinline__ void stout(void* p, int i, float v, int F){
  if (F) ((float*)p)[i] = v; else ((bf16*)p)[i] = f2b(v);
}

// packed chi-count per residue (LETTERS='ARNDCQEGHILKMFPSTWYV'), 3 bits each;
// reference mask is prefix-structured: mask[res][i] = (i < nchi[res]).
#define CHI_PACK ( (0ull<<0)|(4ull<<3)|(2ull<<6)|(2ull<<9)|(1ull<<12)|(3ull<<15)|(3ull<<18)|(0ull<<21) \
                 | (2ull<<24)|(2ull<<27)|(2ull<<30)|(4ull<<33)|(3ull<<36)|(2ull<<39)|(0ull<<42)|(1ull<<45) \
                 | (1ull<<48)|(2ull<<51)|(2ull<<54)|(1ull<<57) )
__device__ __forceinline__ float chi_mask(int res, int i){
  int nchi = (int)((CHI_PACK >> (3*res)) & 7ull);
  return (i < nchi) ? 1.f : 0.f;
}

__device__ __forceinline__ float wsum(float v){
  #pragma unroll
  for (int off = 32; off > 0; off >>= 1) v += __shfl_xor(v, off);
  return v;
}
__device__ __forceinline__ int wor(int v){
  #pragma unroll
  for (int off = 32; off > 0; off >>= 1) v |= __shfl_xor(v, off);
  return v;
}

// ---------------- init: zero counters+diag, probe input dtype ----------------
// diag[0]=stage flags, diag[1]=F (1 if inputs are float32 on the wire)
__global__ __launch_bounds__(256) void k_init(int* cnt, int n, int* dg, const void* scWl){
  int b = blockIdx.x, t = threadIdx.x;
  int i = b*256 + t;
  if (i < n) cnt[i] = 0;
  if (b == 0){
    if (t < 16) dg[t] = 0;
    __syncthreads();
    const bf16* w = (const bf16*)scWl;   // 32768 bf16 = 64KB, in-bounds for either dtype
    int bad = 0;
    for (int k = t; k < 32768; k += 256){
      float x = b2f(w[k]);
      if (!(x==x) || fabsf(x) > 1e30f) bad = 1;
    }
    bad = wor(bad);
    if ((t & 63) == 0 && bad) atomicOr(&dg[1], 1);
  }
}

// ---------------- ws-too-small marker ----------------
__global__ __launch_bounds__(256) void k_mark(void* out){
  int i = blockIdx.x*256 + threadIdx.x;
  if (i < NN) ((float*)out)[i] = 9.0f;
}

// ---------------- embeddings + degree histograms ----------------
__global__ __launch_bounds__(256) void k_pre(
    const void* Xsc, const void* Xbb,
    const void* Wsc, const void* bsc, const void* Wbb, const void* bbb,
    const int* scE, const int* bbE,
    float* sc, float* bbuf, int* cnt_sc, int* cnt_bb, int* dg){
  int b = blockIdx.x, t = threadIdx.x;
  const int F = dg[1];
  if (b < 5000){
    int tid = b*256 + t;
    int node = tid >> 6, d = tid & 63;
    float acc = ldin(bsc, d, F);
    #pragma unroll
    for (int k = 0; k < 21; k++) acc += ldin(Xsc, node*21+k, F) * ldin(Wsc, k*64+d, F);
    sc[tid] = fmaxf(acc, 0.f);
  } else if (b < 10000){
    int tid = (b-5000)*256 + t;
    int node = tid >> 6, d = tid & 63;
    float acc = ldin(bbb, d, F);
    #pragma unroll
    for (int k = 0; k < 12; k++) acc += ldin(Xbb, node*12+k, F) * ldin(Wbb, k*64+d, F);
    bbuf[tid] = fmaxf(acc, 0.f);
  } else if (b < 11250){
    int e = (b-10000)*256 + t;
    int d = scE[NE + e];
    if ((unsigned)d < NN) atomicAdd(&cnt_sc[d], 1); else atomicOr(&dg[0], 128);
  } else {
    int e = (b-11250)*256 + t;
    int d = bbE[NE + e];
    if ((unsigned)d < NN) atomicAdd(&cnt_bb[d], 1); else atomicOr(&dg[0], 128);
  }
}

// ---------------- exclusive scan -> rowptr + cursors ----------------
__global__ __launch_bounds__(256) void k_scan(int* cnt_sc, int* cnt_bb, int* rp_sc, int* rp_bb){
  int* cnt = blockIdx.x ? cnt_bb : cnt_sc;
  int* rp  = blockIdx.x ? rp_bb  : rp_sc;
  __shared__ int s[256];
  const int CH = 79;
  int t = threadIdx.x;
  int beg = t * CH;
  int sum = 0;
  for (int i = beg; i < beg + CH && i < NN; i++) sum += cnt[i];
  s[t] = sum; __syncthreads();
  for (int off = 1; off < 256; off <<= 1){
    int v = (t >= off) ? s[t-off] : 0;
    __syncthreads();
    s[t] += v;
    __syncthreads();
  }
  int run = (t == 0) ? 0 : s[t-1];
  for (int i = beg; i < beg + CH && i < NN; i++){
    int c = cnt[i];
    rp[i] = run;
    cnt[i] = run;      // cursor for scatter
    run += c;
  }
  if (t == 0) rp[NN] = NE;
}

// ---------------- scatter: perm_src + gated sorted edge attrs ----------------
__global__ __launch_bounds__(256) void k_scatter(
    const int* scE, const int* bbE, const int* rid,
    const void* resT, const void* rrW1, const void* rrb1, const void* rrW2, const void* rrb2,
    const void* attrs,
    int* cur_sc, int* cur_bb, int* ps_sc, int* ps_bb, float* ea, int* dg){
  __shared__ float sRT[320], sW1[512], sB1[16], sW2[16];
  __shared__ float sB2;
  int b = blockIdx.x, t = threadIdx.x;
  const int F = dg[1];
  if (b < 1250){
    for (int i = t; i < 320; i += 256) sRT[i] = ldin(resT, i, F);
    for (int i = t; i < 512; i += 256) sW1[i] = ldin(rrW1, i, F);
    if (t < 16){ sB1[t] = ldin(rrb1, t, F); sW2[t] = ldin(rrW2, t, F); }
    if (t == 0) sB2 = ldin(rrb2, 0, F);
    __syncthreads();
    int e = b*256 + t;
    int s = scE[e], d = scE[NE + e];
    if ((unsigned)s >= NN || (unsigned)d >= NN){ atomicOr(&dg[0], 128); return; }
    int rs_i = rid[s], rd_i = rid[d];
    if ((unsigned)rs_i >= 20 || (unsigned)rd_i >= 20){ atomicOr(&dg[0], 128); rs_i = rd_i = 0; }
    const float* rs = &sRT[rs_i*16];
    const float* rd = &sRT[rd_i*16];
    float z = sB2;
    #pragma unroll
    for (int j = 0; j < 16; j++){
      float h = sB1[j];
      #pragma unroll
      for (int i = 0; i < 16; i++) h += rs[i] * sW1[i*16+j];
      #pragma unroll
      for (int i = 0; i < 16; i++) h += rd[i] * sW1[(16+i)*16+j];
      z += fmaxf(h, 0.f) * sW2[j];
    }
    float rel = 1.f / (1.f + __expf(-z));
    int pos = atomicAdd(&cur_sc[d], 1);
    if ((unsigned)pos >= NE){ atomicOr(&dg[0], 4); return; }
    ps_sc[pos] = s;
    #pragma unroll
    for (int j = 0; j < 8; j++) ea[pos*8+j] = ldin(attrs, e*8+j, F) * rel;
  } else {
    int e = (b-1250)*256 + t;
    int s = bbE[e], d = bbE[NE + e];
    if ((unsigned)s >= NN || (unsigned)d >= NN){ atomicOr(&dg[0], 128); return; }
    int pos = atomicAdd(&cur_bb[d], 1);
    if ((unsigned)pos >= NE){ atomicOr(&dg[0], 4); return; }
    ps_bb[pos] = s;
  }
}

// ---------------- per-node matmuls ----------------
__device__ void node_mm(float* sx, const float* x,
                        const void* Wl, const void* Wr, const void* Wres, const void* bias, int l,
                        float* xl, float* xr, float* base, int tile, int F, int* dg){
  int t = threadIdx.x;
  int bad = 0;
  for (int i = t; i < 1024; i += 256){
    float v = x[tile*1024 + i];
    sx[i] = v;
    if (l == 0 && !finitef(v)) bad = 1;
  }
  if (bad) atomicOr(&dg[0], 1);
  __syncthreads();
  int d = t & 63, r = t >> 6;
  int wo = l*4096;
  float aL[4] = {0,0,0,0}, aR[4] = {0,0,0,0}, aB[4];
  float bv = ldin(bias, l*64 + d, F);
  #pragma unroll
  for (int j = 0; j < 4; j++) aB[j] = bv;
  for (int k = 0; k < 64; k++){
    float wl = ldin(Wl, wo + k*64+d, F), wr = ldin(Wr, wo + k*64+d, F), ws = ldin(Wres, wo + k*64+d, F);
    #pragma unroll
    for (int j = 0; j < 4; j++){
      float xv = sx[(r + 4*j)*64 + k];
      aL[j] += xv*wl; aR[j] += xv*wr; aB[j] += xv*ws;
    }
  }
  int n0 = tile*16 + r;
  #pragma unroll
  for (int j = 0; j < 4; j++){
    int n = n0 + 4*j;
    xl[n*64+d] = aL[j]; xr[n*64+d] = aR[j]; base[n*64+d] = aB[j];
  }
}

// grid roles: [0,1250) edge update, [1250,2500) sc node mm, [2500,3750) bb node mm
__global__ __launch_bounds__(256) void k_layer1(
    float* ea, int l,
    const void* euW1, const void* eub1, const void* eug, const void* eube,
    const void* euW2, const void* eub2,
    const float* sc, const float* bbv,
    const void* scWl, const void* scWr, const void* scRes, const void* scBias,
    const void* bbWl, const void* bbWr, const void* bbRes, const void* bbBias,
    float* xl_sc, float* xr_sc, float* bs_sc,
    float* xl_bb, float* xr_bb, float* bs_bb, int* dg){
  __shared__ float smem[1024];
  int b = blockIdx.x, t = threadIdx.x;
  const int F = dg[1];
  if (b < 1250){
    float* sW1 = smem;        float* sB1 = smem+128; float* sG  = smem+144;
    float* sBe = smem+160;    float* sW2 = smem+176; float* sB2 = smem+304;
    for (int i = t; i < 128; i += 256){ sW1[i] = ldin(euW1, l*128+i, F); sW2[i] = ldin(euW2, l*128+i, F); }
    if (t < 16){ sB1[t] = ldin(eub1, l*16+t, F); sG[t] = ldin(eug, l*16+t, F); sBe[t] = ldin(eube, l*16+t, F); }
    if (t < 8) sB2[t] = ldin(eub2, l*8+t, F);
    __syncthreads();
    int e = b*256 + t;
    float a[8];
    int bad = 0;
    #pragma unroll
    for (int i = 0; i < 8; i++){ a[i] = ea[e*8+i]; if (l == 0 && !finitef(a[i])) bad = 1; }
    if (bad) atomicOr(&dg[0], 2);
    float h[16];
    #pragma unroll
    for (int j = 0; j < 16; j++){
      float v = sB1[j];
      #pragma unroll
      for (int i = 0; i < 8; i++) v += a[i] * sW1[i*16+j];
      h[j] = fmaxf(v*BN_C*sG[j] + sBe[j], 0.f);
    }
    #pragma unroll
    for (int i = 0; i < 8; i++){
      float v = sB2[i] + a[i];
      #pragma unroll
      for (int j = 0; j < 16; j++) v += h[j] * sW2[j*8+i];
      ea[e*8+i] = v;
    }
  } else if (b < 2500){
    node_mm(smem, sc, scWl, scWr, scRes, scBias, l, xl_sc, xr_sc, bs_sc, b-1250, F, dg);
  } else {
    node_mm(smem, bbv, bbWl, bbWr, bbRes, bbBias, l, xl_bb, xr_bb, bs_bb, b-2500, F, dg);
  }
}

// ---------------- GAT aggregation (wave per node, online softmax) ----------------
__global__ __launch_bounds__(256) void k_agg(
    float* sc, float* bbv, int l,
    const float* xl_sc, const float* xr_sc, const float* bs_sc,
    const float* xl_bb, const float* xr_bb, const float* bs_bb,
    const int* rp_sc, const int* ps_sc, const int* rp_bb, const int* ps_bb,
    const float* ea, const void* We, const void* scAtt, const void* bbAtt, int* dg){
  int b = blockIdx.x;
  int lane = threadIdx.x & 63, wid = threadIdx.x >> 6;
  const int F = dg[1];
  bool is_sc = b < 5000;
  int n = (is_sc ? b : b - 5000)*4 + wid;
  const float* xl = is_sc ? xl_sc : xl_bb;
  const float* xr = is_sc ? xr_sc : xr_bb;
  const float* bs = is_sc ? bs_sc : bs_bb;
  const int* rp = is_sc ? rp_sc : rp_bb;
  const int* ps = is_sc ? ps_sc : ps_bb;
  float attv = is_sc ? ldin(scAtt, l*64+lane, F) : ldin(bbAtt, l*64+lane, F);
  float w0=0,w1=0,w2=0,w3=0,w4=0,w5=0,w6=0,w7=0;
  if (is_sc){
    int o = l*512 + lane;
    w0=ldin(We,o,F); w1=ldin(We,o+64,F); w2=ldin(We,o+128,F); w3=ldin(We,o+192,F);
    w4=ldin(We,o+256,F); w5=ldin(We,o+320,F); w6=ldin(We,o+384,F); w7=ldin(We,o+448,F);
  }
  int beg = rp[n], end = rp[n+1];
  int bflag = 0;
  if (beg < 0 || end < beg || end > NE){ bflag |= 4; beg = end = 0; }
  float xrv = xr[n*64+lane];
  float o = 0.f, s = 0.f, mx = -3.0e38f;
  for (int eid = beg; eid < end; ++eid){
    int sn = ps[eid];
    if ((unsigned)sn >= NN){ bflag |= 4; continue; }
    float v = xl[sn*64+lane];
    float m = v + xrv;
    if (is_sc){
      const float4* a4 = (const float4*)(ea + eid*8);
      float4 A = a4[0], B = a4[1];
      m += A.x*w0 + A.y*w1 + A.z*w2 + A.w*w3 + B.x*w4 + B.y*w5 + B.z*w6 + B.w*w7;
    }
    if (!finitef(m)) bflag |= 8;
    float lk = fmaxf(m, 0.f) + 0.2f*fminf(m, 0.f);
    float e = wsum(lk * attv);
    if (!finitef(e)) bflag |= 16;
    float nm = fmaxf(mx, e);
    float scl = __expf(mx - nm);
    float pe  = __expf(e - nm);
    o = o*scl + pe*v;
    s = s*scl + pe;
    mx = nm;
  }
  bflag = wor(bflag);
  if (lane == 0 && bflag) atomicOr(&dg[0], bflag);
  float* outp = is_sc ? sc : bbv;
  outp[n*64+lane] = o/(s + 1e-16f) + bs[n*64+lane];
}

// ---------------- fusion (bb += attn*sc_up) + v_com head ----------------
__global__ __launch_bounds__(256) void k_fusion(
    const float* sc, float* bbv,
    const void* bnuW, const void* bnub, const void* bnug, const void* bnube,
    const void* afW, const void* afb, const void* afg, const void* afbe,
    const void* vcW1, const void* vcb1, const void* vcW2, const void* vcb2,
    void* out, int* dg){
  __shared__ float sx[1024];
  __shared__ int sbad;
  int b = blockIdx.x, t = threadIdx.x;
  const int F = dg[1];
  int d = t & 63, r = t >> 6;
  if (t == 0) sbad = dg[0];
  int bad = 0;
  for (int i = t; i < 1024; i += 256){ float v = sc[b*1024 + i]; sx[i] = v; if (!finitef(v)) bad = 1; }
  if (bad){ atomicOr(&dg[0], 32); atomicOr(&sbad, 32); }
  __syncthreads();
  int fl = sbad;
  float M = 4.0f + (float)(fl & 255);
  float aU[4] = {0,0,0,0}, aV[4] = {0,0,0,0};
  for (int k = 0; k < 64; k++){
    float wu = ldin(bnuW, k*64+d, F), wv = ldin(vcW1, k*64+d, F);
    #pragma unroll
    for (int j = 0; j < 4; j++){
      float xv = sx[(r + 4*j)*64 + k];
      aU[j] += xv*wu; aV[j] += xv*wv;
    }
  }
  float afwd = ldin(afW, d, F);
  float bnubd = ldin(bnub, d, F), bnugd = ldin(bnug, d, F), bnubed = ldin(bnube, d, F);
  float vcb1d = ldin(vcb1, d, F);
  float afbv = ldin(afb, 0, F), afgv = ldin(afg, 0, F), afbev = ldin(afbe, 0, F);
  #pragma unroll
  for (int j = 0; j < 4; j++){
    int node = b*16 + r + 4*j;
    float z = wsum(sx[(r + 4*j)*64 + d] * afwd);
    float attn = 1.f / (1.f + __expf(-((z + afbv)*BN_C*afgv + afbev)));
    float u = fmaxf((aU[j] + bnubd)*BN_C*bnugd + bnubed, 0.f);
    bbv[node*64+d] += attn*u;
    float vh = fmaxf(aV[j] + vcb1d, 0.f);
    #pragma unroll
    for (int c = 0; c < 3; c++){
      float p = wsum(vh * ldin(vcW2, d*3+c, F));
      if (d == 0) stout(out, 4*NN + node*3 + c, fl ? M : (p + ldin(vcb2, c, F)), F);
    }
  }
}

// ---------------- chi heads (sc) + backbone heads (bb) ----------------
__global__ __launch_bounds__(256) void k_heads(
    const float* sc, const float* bbv, const int* rid,
    const void* chiW, const void* chib, const void* adW1, const void* adW2,
    const void* bbhW1, const void* bbhb1, const void* phiW2, const void* psiW2,
    const void* xcaW2, const void* xcab2, const void* vcbW2, const void* vcbb2,
    void* out, int* dg){
  __shared__ float sx[1024];
  __shared__ float sh[1024];
  __shared__ int srid[16];
  __shared__ int sbad;
  int b = blockIdx.x, t = threadIdx.x;
  const int F = dg[1];
  int d = t & 63, r = t >> 6;
  if (t == 0) sbad = dg[0];
  if (b < 1250){
    int tile = b;
    int bad = 0;
    for (int i = t; i < 1024; i += 256){ float v = sc[tile*1024 + i]; sx[i] = v; if (!finitef(v)) bad = 1; }
    if (t < 16){
      int rv = rid[tile*16 + t];
      if ((unsigned)rv >= 20){ rv = 0; bad |= 1; }
      srid[t] = rv;
    }
    if (bad){ atomicOr(&dg[0], 32); atomicOr(&sbad, 32); }
    __syncthreads();
    int fl = sbad;
    float M = 4.0f + (float)(fl & 255);
    for (int i = 0; i < 4; i++){
      float acc[4] = {0,0,0,0};
      for (int k = 0; k < 64; k++){
        float w = ldin(chiW, i*4096 + k*64+d, F);
        #pragma unroll
        for (int j = 0; j < 4; j++) acc[j] += sx[(r + 4*j)*64 + k] * w;
      }
      float bi = ldin(chib, i*64+d, F);
      #pragma unroll
      for (int j = 0; j < 4; j++){
        float mk = chi_mask(srid[r + 4*j], i);
        sh[(r + 4*j)*64 + d] = fmaxf(acc[j] + bi, 0.f) * mk;
      }
      __syncthreads();
      float a2[4] = {0,0,0,0};
      for (int k = 0; k < 64; k++){
        float w = ldin(adW1, k*64+d, F);
        #pragma unroll
        for (int j = 0; j < 4; j++) a2[j] += sh[(r + 4*j)*64 + k] * w;
      }
      float w2 = ldin(adW2, d, F);
      #pragma unroll
      for (int j = 0; j < 4; j++){
        float p = wsum(fmaxf(a2[j], 0.f) * w2);
        if (d == 0) stout(out, i*NN + tile*16 + r + 4*j, fl ? M : p, F);
      }
      __syncthreads();
    }
  } else {
    int tile = b - 1250;
    int bad = 0;
    for (int i = t; i < 1024; i += 256){ float v = bbv[tile*1024 + i]; sx[i] = v; if (!finitef(v)) bad = 1; }
    if (bad){ atomicOr(&dg[0], 32); atomicOr(&sbad, 32); }
    __syncthreads();
    int fl = sbad;
    float M = 4.0f + (float)(fl & 255);
    for (int i = 0; i < 4; i++){
      float acc[4] = {0,0,0,0};
      for (int k = 0; k < 64; k++){
        float w = ldin(bbhW1, i*4096 + k*64+d, F);
        #pragma unroll
        for (int j = 0; j < 4; j++) acc[j] += sx[(r + 4*j)*64 + k] * w;
      }
      float bi = ldin(bbhb1, i*64+d, F);
      if (i < 2){
        float w2 = (i == 0) ? ldin(phiW2, d, F) : ldin(psiW2, d, F);
        #pragma unroll
        for (int j = 0; j < 4; j++){
          float p = wsum(fmaxf(acc[j] + bi, 0.f) * w2);
          if (d == 0) stout(out, (7+i)*NN + tile*16 + r + 4*j, fl ? M : p, F);
        }
      } else {
        const void* W2 = (i == 2) ? xcaW2 : vcbW2;
        const void* B2 = (i == 2) ? xcab2 : vcbb2;
        int off = (i == 2) ? 9*NN : 12*NN;
        #pragma unroll
        for (int j = 0; j < 4; j++){
          float h = fmaxf(acc[j] + bi, 0.f);
          #pragma unroll
          for (int c = 0; c < 3; c++){
            float p = wsum(h * ldin(W2, d*3+c, F));
            if (d == 0) stout(out, off + (tile*16 + r + 4*j)*3 + c, fl ? M : (p + ldin(B2, c, F)), F);
          }
        }
      }
    }
  }
}

extern "C" __attribute__((visibility("default")))
void kernel_launch(void* const* d_in, const int* in_sizes, int n_in,
                   void* d_out, int out_size, void* d_ws, size_t ws_size,
                   hipStream_t stream) {
  (void)hipGetLastError();

  const void* Xsc   = d_in[0];
  const void* Xbb   = d_in[1];
  const void* attrs = d_in[2];
  const int*  scE   = (const int*)d_in[3];
  const int*  bbE   = (const int*)d_in[4];
  const int*  rid   = (const int*)d_in[5];
  const void* scembW=d_in[6];  const void* scembb=d_in[7];
  const void* bbembW=d_in[8];  const void* bbembb=d_in[9];
  const void* resT  =d_in[10];
  const void* rrW1  =d_in[11]; const void* rrb1  =d_in[12];
  const void* rrW2  =d_in[13]; const void* rrb2  =d_in[14];
  const void* scWl  =d_in[15]; const void* scWr  =d_in[16];
  const void* scWe  =d_in[17]; const void* scAtt =d_in[18];
  const void* scRes =d_in[19]; const void* scBias=d_in[20];
  const void* bbWl  =d_in[21]; const void* bbWr  =d_in[22];
  const void* bbAtt =d_in[23]; const void* bbRes =d_in[24];
  const void* bbBias=d_in[25];
  const void* euW1  =d_in[26]; const void* eub1  =d_in[27];
  const void* eug   =d_in[28]; const void* eube  =d_in[29];
  const void* euW2  =d_in[30]; const void* eub2  =d_in[31];
  const void* bnuW  =d_in[32]; const void* bnub  =d_in[33];
  const void* bnug  =d_in[34]; const void* bnube =d_in[35];
  const void* afW   =d_in[36]; const void* afb   =d_in[37];
  const void* afg   =d_in[38]; const void* afbe  =d_in[39];
  const void* chiW  =d_in[40]; const void* chib  =d_in[41];
  const void* adW1  =d_in[42]; const void* adW2  =d_in[43];
  const void* vcW1  =d_in[44]; const void* vcb1  =d_in[45];
  const void* vcW2  =d_in[46]; const void* vcb2  =d_in[47];
  const void* bbhW1 =d_in[48]; const void* bbhb1 =d_in[49];
  const void* phiW2 =d_in[50]; const void* psiW2 =d_in[51];
  const void* xcaW2 =d_in[52]; const void* xcab2 =d_in[53];
  const void* vcbW2 =d_in[54]; const void* vcbb2 =d_in[55];

  // workspace layout: diag (64B) | floats | ints
  size_t need = 64 + (size_t)(8*NN*64 + NE*8)*4 + (size_t)(2*(NN+1) + 2*NN + 2*NE)*4;
  if (ws_size < need){
    k_mark<<<(NN+255)/256, 256, 0, stream>>>(d_out);
    return;
  }
  int* dg = (int*)d_ws;
  float* f = (float*)((char*)d_ws + 64);
  float* sc    = f; f += NN*64;
  float* bbuf  = f; f += NN*64;
  float* xl_sc = f; f += NN*64;
  float* xr_sc = f; f += NN*64;
  float* bs_sc = f; f += NN*64;
  float* xl_bb = f; f += NN*64;
  float* xr_bb = f; f += NN*64;
  float* bs_bb = f; f += NN*64;
  float* ea    = f; f += NE*8;
  int* ip = (int*)f;
  int* rp_sc  = ip; ip += NN+1;
  int* rp_bb  = ip; ip += NN+1;
  int* cnt_sc = ip; ip += NN;
  int* cnt_bb = ip; ip += NN;
  int* ps_sc  = ip; ip += NE;
  int* ps_bb  = ip; ip += NE;

  k_init<<<(2*NN + 255)/256, 256, 0, stream>>>(cnt_sc, 2*NN, dg, scWl);
  k_pre<<<12500, 256, 0, stream>>>(Xsc, Xbb, scembW, scembb, bbembW, bbembb,
                                   scE, bbE, sc, bbuf, cnt_sc, cnt_bb, dg);
  k_scan<<<2, 256, 0, stream>>>(cnt_sc, cnt_bb, rp_sc, rp_bb);
  k_scatter<<<2500, 256, 0, stream>>>(scE, bbE, rid, resT, rrW1, rrb1, rrW2, rrb2,
                                      attrs, cnt_sc, cnt_bb, ps_sc, ps_bb, ea, dg);
  for (int l = 0; l < NL; l++){
    k_layer1<<<3750, 256, 0, stream>>>(ea, l,
        euW1, eub1, eug, eube, euW2, eub2,
        sc, bbuf,
        scWl, scWr, scRes, scBias,
        bbWl, bbWr, bbRes, bbBias,
        xl_sc, xr_sc, bs_sc, xl_bb, xr_bb, bs_bb, dg);
    k_agg<<<10000, 256, 0, stream>>>(sc, bbuf, l,
        xl_sc, xr_sc, bs_sc, xl_bb, xr_bb, bs_bb,
        rp_sc, ps_sc, rp_bb, ps_bb,
        ea, scWe, scAtt, bbAtt, dg);
  }
  k_fusion<<<1250, 256, 0, stream>>>(sc, bbuf,
      bnuW, bnub, bnug, bnube, afW, afb, afg, afbe,
      vcW1, vcb1, vcW2, vcb2, d_out, dg);
  k_heads<<<2500, 256, 0, stream>>>(sc, bbuf, rid,
      chiW, chib, adW1, adW2, bbhW1, bbhb1,
      phiW2, psiW2, xcaW2, xcab2, vcbW2, vcbb2, d_out, dg);
}

// Round 6
// 1625.553 us; speedup vs baseline: 1.3860x; 1.3860x over previous
//
#include <hip/hip_runtime.h>
#include <hip/hip_bf16.h>

#define NN 20000
#define NE 320000
#define NL 12
#define BN_C 0.9999950000374997f

// Inputs/outputs are float32 on the wire (proven R5: dtype probe set F=1 and
// the run passed at absmax 1.5e-5; bf16 wire would have NaN-flooded).

// packed chi-count per residue (LETTERS='ARNDCQEGHILKMFPSTWYV'), 3 bits each;
// reference mask is prefix-structured: mask[res][i] = (i < nchi[res]).
#define CHI_PACK ( (0ull<<0)|(4ull<<3)|(2ull<<6)|(2ull<<9)|(1ull<<12)|(3ull<<15)|(3ull<<18)|(0ull<<21) \
                 | (2ull<<24)|(2ull<<27)|(2ull<<30)|(4ull<<33)|(3ull<<36)|(2ull<<39)|(0ull<<42)|(1ull<<45) \
                 | (1ull<<48)|(2ull<<51)|(2ull<<54)|(1ull<<57) )
__device__ __forceinline__ float chi_mask(int res, int i){
  int nchi = (int)((CHI_PACK >> (3*res)) & 7ull);
  return (i < nchi) ? 1.f : 0.f;
}

__device__ __forceinline__ float wsum(float v){
  #pragma unroll
  for (int off = 32; off > 0; off >>= 1) v += __shfl_xor(v, off);
  return v;
}

// ---------------- zero counters ----------------
__global__ __launch_bounds__(256) void k_init(int* p, int n){
  int i = blockIdx.x*256 + threadIdx.x;
  if (i < n) p[i] = 0;
}

// ---------------- ws-too-small marker ----------------
__global__ __launch_bounds__(256) void k_mark(float* out){
  int i = blockIdx.x*256 + threadIdx.x;
  if (i < NN) out[i] = 9.0f;
}

// ---------------- embeddings + degree histograms ----------------
// grid: [0,5000) sc embed, [5000,10000) bb embed, [10000,11250) sc hist, [11250,12500) bb hist
__global__ __launch_bounds__(256) void k_pre(
    const float* __restrict__ Xsc, const float* __restrict__ Xbb,
    const float* __restrict__ Wsc, const float* __restrict__ bsc,
    const float* __restrict__ Wbb, const float* __restrict__ bbb,
    const int* __restrict__ scE, const int* __restrict__ bbE,
    float* __restrict__ sc, float* __restrict__ bbuf, int* cnt_sc, int* cnt_bb){
  int b = blockIdx.x, t = threadIdx.x;
  if (b < 5000){
    int tid = b*256 + t;
    int node = tid >> 6, d = tid & 63;
    float acc = bsc[d];
    #pragma unroll
    for (int k = 0; k < 21; k++) acc += Xsc[node*21+k] * Wsc[k*64+d];
    sc[tid] = fmaxf(acc, 0.f);
  } else if (b < 10000){
    int tid = (b-5000)*256 + t;
    int node = tid >> 6, d = tid & 63;
    float acc = bbb[d];
    #pragma unroll
    for (int k = 0; k < 12; k++) acc += Xbb[node*12+k] * Wbb[k*64+d];
    bbuf[tid] = fmaxf(acc, 0.f);
  } else if (b < 11250){
    int e = (b-10000)*256 + t;
    atomicAdd(&cnt_sc[scE[NE + e]], 1);
  } else {
    int e = (b-11250)*256 + t;
    atomicAdd(&cnt_bb[bbE[NE + e]], 1);
  }
}

// ---------------- scan (blocks 0,1) + rel-gate table (block 2) ----------------
// rel depends only on (rid[src],rid[dst]) -> 400 pairs, precompute once.
__global__ __launch_bounds__(256) void k_scan(
    int* cnt_sc, int* cnt_bb, int* rp_sc, int* rp_bb,
    const float* __restrict__ resT, const float* __restrict__ rrW1,
    const float* __restrict__ rrb1, const float* __restrict__ rrW2,
    const float* __restrict__ rrb2, float* relTab){
  int t = threadIdx.x;
  if (blockIdx.x == 2){
    __shared__ float sRT[320], sW1[512], sB1[16], sW2[16];
    for (int i = t; i < 320; i += 256) sRT[i] = resT[i];
    for (int i = t; i < 512; i += 256) sW1[i] = rrW1[i];
    if (t < 16){ sB1[t] = rrb1[t]; sW2[t] = rrW2[t]; }
    __syncthreads();
    float b2v = rrb2[0];
    for (int p = t; p < 400; p += 256){
      int a = p / 20, c = p % 20;
      const float* ra = &sRT[a*16];
      const float* rc = &sRT[c*16];
      float z = b2v;
      #pragma unroll
      for (int j = 0; j < 16; j++){
        float h = sB1[j];
        #pragma unroll
        for (int i = 0; i < 16; i++) h += ra[i] * sW1[i*16+j];
        #pragma unroll
        for (int i = 0; i < 16; i++) h += rc[i] * sW1[(16+i)*16+j];
        z += fmaxf(h, 0.f) * sW2[j];
      }
      relTab[p] = 1.f / (1.f + __expf(-z));
    }
    return;
  }
  int* cnt = blockIdx.x ? cnt_bb : cnt_sc;
  int* rp  = blockIdx.x ? rp_bb  : rp_sc;
  __shared__ int s[256];
  const int CH = 79;
  int beg = t * CH;
  int sum = 0;
  for (int i = beg; i < beg + CH && i < NN; i++) sum += cnt[i];
  s[t] = sum; __syncthreads();
  for (int off = 1; off < 256; off <<= 1){
    int v = (t >= off) ? s[t-off] : 0;
    __syncthreads();
    s[t] += v;
    __syncthreads();
  }
  int run = (t == 0) ? 0 : s[t-1];
  for (int i = beg; i < beg + CH && i < NN; i++){
    int c = cnt[i];
    rp[i] = run;
    cnt[i] = run;      // cursor for scatter
    run += c;
  }
  if (t == 0) rp[NN] = NE;
}

// ---------------- scatter: perm_src + gated sorted edge attrs ----------------
// grid: [0,1250) sc edges, [1250,2500) bb edges
__global__ __launch_bounds__(256) void k_scatter(
    const int* __restrict__ scE, const int* __restrict__ bbE, const int* __restrict__ rid,
    const float* __restrict__ relTab, const float* __restrict__ attrs,
    int* cur_sc, int* cur_bb, int* __restrict__ ps_sc, int* __restrict__ ps_bb,
    float* __restrict__ ea){
  int b = blockIdx.x, t = threadIdx.x;
  if (b < 1250){
    int e = b*256 + t;
    int s = scE[e], d = scE[NE + e];
    float rel = relTab[rid[s]*20 + rid[d]];
    float4 A = ((const float4*)attrs)[e*2];
    float4 B = ((const float4*)attrs)[e*2+1];
    A.x *= rel; A.y *= rel; A.z *= rel; A.w *= rel;
    B.x *= rel; B.y *= rel; B.z *= rel; B.w *= rel;
    int pos = atomicAdd(&cur_sc[d], 1);
    ps_sc[pos] = s;
    ((float4*)ea)[pos*2]   = A;
    ((float4*)ea)[pos*2+1] = B;
  } else {
    int e = (b-1250)*256 + t;
    int s = bbE[e], d = bbE[NE + e];
    int pos = atomicAdd(&cur_bb[d], 1);
    ps_bb[pos] = s;
  }
}

// ---------------- per-node matmuls: xl = x@Wl, xr = x@Wr, base = bias + x@Wres ----------------
__device__ void node_mm(float* sx, const float* __restrict__ x,
                        const float* __restrict__ Wl, const float* __restrict__ Wr,
                        const float* __restrict__ Wres, const float* __restrict__ bias, int l,
                        float* __restrict__ xl, float* __restrict__ xr, float* __restrict__ base,
                        int tile){
  int t = threadIdx.x;
  for (int i = t; i < 1024; i += 256) sx[i] = x[tile*1024 + i];
  __syncthreads();
  int d = t & 63, r = t >> 6;
  int wo = l*4096 + d;
  float aL[4] = {0,0,0,0}, aR[4] = {0,0,0,0}, aB[4];
  float bv = bias[l*64 + d];
  #pragma unroll
  for (int j = 0; j < 4; j++) aB[j] = bv;
  #pragma unroll 4
  for (int k = 0; k < 64; k++){
    float wl = Wl[wo + k*64], wr = Wr[wo + k*64], ws = Wres[wo + k*64];
    #pragma unroll
    for (int j = 0; j < 4; j++){
      float xv = sx[(r + 4*j)*64 + k];
      aL[j] += xv*wl; aR[j] += xv*wr; aB[j] += xv*ws;
    }
  }
  int n0 = tile*16 + r;
  #pragma unroll
  for (int j = 0; j < 4; j++){
    int n = n0 + 4*j;
    xl[n*64+d] = aL[j]; xr[n*64+d] = aR[j]; base[n*64+d] = aB[j];
  }
}

// grid roles: [0,1250) edge update, [1250,2500) sc node mm, [2500,3750) bb node mm
__global__ __launch_bounds__(256) void k_layer1(
    float* __restrict__ ea, int l,
    const float* __restrict__ euW1, const float* __restrict__ eub1,
    const float* __restrict__ eug, const float* __restrict__ eube,
    const float* __restrict__ euW2, const float* __restrict__ eub2,
    const float* __restrict__ sc, const float* __restrict__ bbv,
    const float* __restrict__ scWl, const float* __restrict__ scWr,
    const float* __restrict__ scRes, const float* __restrict__ scBias,
    const float* __restrict__ bbWl, const float* __restrict__ bbWr,
    const float* __restrict__ bbRes, const float* __restrict__ bbBias,
    float* __restrict__ xl_sc, float* __restrict__ xr_sc, float* __restrict__ bs_sc,
    float* __restrict__ xl_bb, float* __restrict__ xr_bb, float* __restrict__ bs_bb){
  __shared__ float smem[1024];
  int b = blockIdx.x, t = threadIdx.x;
  if (b < 1250){
    float* sW1 = smem;        float* sB1 = smem+128; float* sG  = smem+144;
    float* sBe = smem+160;    float* sW2 = smem+176; float* sB2 = smem+304;
    for (int i = t; i < 128; i += 256){ sW1[i] = euW1[l*128+i]; sW2[i] = euW2[l*128+i]; }
    if (t < 16){ sB1[t] = eub1[l*16+t]; sG[t] = eug[l*16+t]; sBe[t] = eube[l*16+t]; }
    if (t < 8) sB2[t] = eub2[l*8+t];
    __syncthreads();
    int e = b*256 + t;
    float4 A = ((const float4*)ea)[e*2];
    float4 B = ((const float4*)ea)[e*2+1];
    float a[8] = {A.x,A.y,A.z,A.w,B.x,B.y,B.z,B.w};
    float h[16];
    #pragma unroll
    for (int j = 0; j < 16; j++){
      float v = sB1[j];
      #pragma unroll
      for (int i = 0; i < 8; i++) v += a[i] * sW1[i*16+j];
      h[j] = fmaxf(v*BN_C*sG[j] + sBe[j], 0.f);
    }
    #pragma unroll
    for (int i = 0; i < 8; i++){
      float v = sB2[i] + a[i];
      #pragma unroll
      for (int j = 0; j < 16; j++) v += h[j] * sW2[j*8+i];
      a[i] = v;
    }
    ((float4*)ea)[e*2]   = make_float4(a[0],a[1],a[2],a[3]);
    ((float4*)ea)[e*2+1] = make_float4(a[4],a[5],a[6],a[7]);
  } else if (b < 2500){
    node_mm(smem, sc, scWl, scWr, scRes, scBias, l, xl_sc, xr_sc, bs_sc, b-1250);
  } else {
    node_mm(smem, bbv, bbWl, bbWr, bbRes, bbBias, l, xl_bb, xr_bb, bs_bb, b-2500);
  }
}

// ---------------- GAT aggregation (wave per node, online softmax, unroll x2) ----------------
// grid: [0,5000) sc graph, [5000,10000) bb graph; 4 waves/block
__global__ __launch_bounds__(256) void k_agg(
    float* __restrict__ sc, float* __restrict__ bbv, int l,
    const float* __restrict__ xl_sc, const float* __restrict__ xr_sc, const float* __restrict__ bs_sc,
    const float* __restrict__ xl_bb, const float* __restrict__ xr_bb, const float* __restrict__ bs_bb,
    const int* __restrict__ rp_sc, const int* __restrict__ ps_sc,
    const int* __restrict__ rp_bb, const int* __restrict__ ps_bb,
    const float* __restrict__ ea, const float* __restrict__ We,
    const float* __restrict__ scAtt, const float* __restrict__ bbAtt){
  int b = blockIdx.x;
  int lane = threadIdx.x & 63, wid = threadIdx.x >> 6;
  bool is_sc = b < 5000;
  int n = (is_sc ? b : b - 5000)*4 + wid;
  const float* xl = is_sc ? xl_sc : xl_bb;
  const float* xr = is_sc ? xr_sc : xr_bb;
  const float* bs = is_sc ? bs_sc : bs_bb;
  const int* rp = is_sc ? rp_sc : rp_bb;
  const int* ps = is_sc ? ps_sc : ps_bb;
  float attv = is_sc ? scAtt[l*64+lane] : bbAtt[l*64+lane];
  float w0=0,w1=0,w2=0,w3=0,w4=0,w5=0,w6=0,w7=0;
  if (is_sc){
    int o = l*512 + lane;
    w0=We[o]; w1=We[o+64]; w2=We[o+128]; w3=We[o+192];
    w4=We[o+256]; w5=We[o+320]; w6=We[o+384]; w7=We[o+448];
  }
  int beg = rp[n], end = rp[n+1];
  float xrv = xr[n*64+lane];
  float o = 0.f, s = 0.f, mx = -3.0e38f;
  int eid = beg;
  for (; eid + 2 <= end; eid += 2){
    int sn0 = ps[eid], sn1 = ps[eid+1];
    float v0 = xl[sn0*64+lane];
    float v1 = xl[sn1*64+lane];
    float m0 = v0 + xrv, m1 = v1 + xrv;
    if (is_sc){
      const float4* a4 = (const float4*)(ea + eid*8);
      float4 A0 = a4[0], B0 = a4[1], A1 = a4[2], B1 = a4[3];
      m0 += A0.x*w0 + A0.y*w1 + A0.z*w2 + A0.w*w3 + B0.x*w4 + B0.y*w5 + B0.z*w6 + B0.w*w7;
      m1 += A1.x*w0 + A1.y*w1 + A1.z*w2 + A1.w*w3 + B1.x*w4 + B1.y*w5 + B1.z*w6 + B1.w*w7;
    }
    float e0 = (fmaxf(m0, 0.f) + 0.2f*fminf(m0, 0.f)) * attv;
    float e1 = (fmaxf(m1, 0.f) + 0.2f*fminf(m1, 0.f)) * attv;
    #pragma unroll
    for (int off = 32; off > 0; off >>= 1){
      e0 += __shfl_xor(e0, off);
      e1 += __shfl_xor(e1, off);
    }
    float nm = fmaxf(mx, fmaxf(e0, e1));
    float scl = __expf(mx - nm);
    float p0  = __expf(e0 - nm);
    float p1  = __expf(e1 - nm);
    o = o*scl + p0*v0 + p1*v1;
    s = s*scl + p0 + p1;
    mx = nm;
  }
  if (eid < end){
    int sn = ps[eid];
    float v = xl[sn*64+lane];
    float m = v + xrv;
    if (is_sc){
      const float4* a4 = (const float4*)(ea + eid*8);
      float4 A = a4[0], B = a4[1];
      m += A.x*w0 + A.y*w1 + A.z*w2 + A.w*w3 + B.x*w4 + B.y*w5 + B.z*w6 + B.w*w7;
    }
    float e = wsum((fmaxf(m, 0.f) + 0.2f*fminf(m, 0.f)) * attv);
    float nm = fmaxf(mx, e);
    float scl = __expf(mx - nm);
    float pe  = __expf(e - nm);
    o = o*scl + pe*v;
    s = s*scl + pe;
    mx = nm;
  }
  float* outp = is_sc ? sc : bbv;
  outp[n*64+lane] = o/(s + 1e-16f) + bs[n*64+lane];
}

// ---------------- heads: chi (sc) | fusion + v_com + backbone heads (bb) ----------------
// grid: [0,1250) chi, [1250,2500) fusion+bb heads
__global__ __launch_bounds__(256) void k_heads(
    const float* __restrict__ sc, const float* __restrict__ bbv, const int* __restrict__ rid,
    const float* __restrict__ bnuW, const float* __restrict__ bnub,
    const float* __restrict__ bnug, const float* __restrict__ bnube,
    const float* __restrict__ afW, const float* __restrict__ afb,
    const float* __restrict__ afg, const float* __restrict__ afbe,
    const float* __restrict__ vcW1, const float* __restrict__ vcb1,
    const float* __restrict__ vcW2, const float* __restrict__ vcb2,
    const float* __restrict__ chiW, const float* __restrict__ chib,
    const float* __restrict__ adW1, const float* __restrict__ adW2,
    const float* __restrict__ bbhW1, const float* __restrict__ bbhb1,
    const float* __restrict__ phiW2, const float* __restrict__ psiW2,
    const float* __restrict__ xcaW2, const float* __restrict__ xcab2,
    const float* __restrict__ vcbW2, const float* __restrict__ vcbb2,
    float* __restrict__ out){
  __shared__ float sx[1024];
  __shared__ float sh[1024];
  __shared__ int srid[16];
  int b = blockIdx.x, t = threadIdx.x;
  int d = t & 63, r = t >> 6;
  if (b < 1250){
    int tile = b;
    for (int i = t; i < 1024; i += 256) sx[i] = sc[tile*1024 + i];
    if (t < 16) srid[t] = rid[tile*16 + t];
    __syncthreads();
    for (int i = 0; i < 4; i++){
      const float* W = chiW + i*4096;
      float acc[4] = {0,0,0,0};
      #pragma unroll 4
      for (int k = 0; k < 64; k++){
        float w = W[k*64+d];
        #pragma unroll
        for (int j = 0; j < 4; j++) acc[j] += sx[(r + 4*j)*64 + k] * w;
      }
      float bi = chib[i*64+d];
      #pragma unroll
      for (int j = 0; j < 4; j++){
        float mk = chi_mask(srid[r + 4*j], i);
        sh[(r + 4*j)*64 + d] = fmaxf(acc[j] + bi, 0.f) * mk;
      }
      __syncthreads();
      float a2[4] = {0,0,0,0};
      #pragma unroll 4
      for (int k = 0; k < 64; k++){
        float w = adW1[k*64+d];
        #pragma unroll
        for (int j = 0; j < 4; j++) a2[j] += sh[(r + 4*j)*64 + k] * w;
      }
      float w2 = adW2[d];
      #pragma unroll
      for (int j = 0; j < 4; j++){
        float p = wsum(fmaxf(a2[j], 0.f) * w2);
        if (d == 0) out[i*NN + tile*16 + r + 4*j] = p;
      }
      __syncthreads();
    }
  } else {
    int tile = b - 1250;
    // sx = sc tile, sh = bb tile (updated in-place by fusion)
    for (int i = t; i < 1024; i += 256){ sx[i] = sc[tile*1024 + i]; sh[i] = bbv[tile*1024 + i]; }
    __syncthreads();
    // fusion: bb += sigmoid(bn(sc@afW+afb)) * relu(bn(sc@bnuW+bnub))  +  v_com head
    float aU[4] = {0,0,0,0}, aV[4] = {0,0,0,0};
    #pragma unroll 4
    for (int k = 0; k < 64; k++){
      float wu = bnuW[k*64+d], wv = vcW1[k*64+d];
      #pragma unroll
      for (int j = 0; j < 4; j++){
        float xv = sx[(r + 4*j)*64 + k];
        aU[j] += xv*wu; aV[j] += xv*wv;
      }
    }
    float afwd = afW[d];
    float bnubd = bnub[d], bnugd = bnug[d], bnubed = bnube[d];
    float vcb1d = vcb1[d];
    float afbv = afb[0], afgv = afg[0], afbev = afbe[0];
    #pragma unroll
    for (int j = 0; j < 4; j++){
      int node = tile*16 + r + 4*j;
      float z = wsum(sx[(r + 4*j)*64 + d] * afwd);
      float attn = 1.f / (1.f + __expf(-((z + afbv)*BN_C*afgv + afbev)));
      float u = fmaxf((aU[j] + bnubd)*BN_C*bnugd + bnubed, 0.f);
      sh[(r + 4*j)*64 + d] += attn*u;
      float vh = fmaxf(aV[j] + vcb1d, 0.f);
      #pragma unroll
      for (int c = 0; c < 3; c++){
        float p = wsum(vh * vcW2[d*3+c]);
        if (d == 0) out[4*NN + node*3 + c] = p + vcb2[c];
      }
    }
    __syncthreads();
    // backbone heads from fused bb (sh)
    for (int i = 0; i < 4; i++){
      const float* W = bbhW1 + i*4096;
      float acc[4] = {0,0,0,0};
      #pragma unroll 4
      for (int k = 0; k < 64; k++){
        float w = W[k*64+d];
        #pragma unroll
        for (int j = 0; j < 4; j++) acc[j] += sh[(r + 4*j)*64 + k] * w;
      }
      float bi = bbhb1[i*64+d];
      if (i < 2){
        float w2 = (i == 0) ? phiW2[d] : psiW2[d];
        #pragma unroll
        for (int j = 0; j < 4; j++){
          float p = wsum(fmaxf(acc[j] + bi, 0.f) * w2);
          if (d == 0) out[(7+i)*NN + tile*16 + r + 4*j] = p;
        }
      } else {
        const float* W2 = (i == 2) ? xcaW2 : vcbW2;
        const float* B2 = (i == 2) ? xcab2 : vcbb2;
        int off = (i == 2) ? 9*NN : 12*NN;
        #pragma unroll
        for (int j = 0; j < 4; j++){
          float h = fmaxf(acc[j] + bi, 0.f);
          #pragma unroll
          for (int c = 0; c < 3; c++){
            float p = wsum(h * W2[d*3+c]);
            if (d == 0) out[off + (tile*16 + r + 4*j)*3 + c] = p + B2[c];
          }
        }
      }
    }
  }
}

extern "C" __attribute__((visibility("default")))
void kernel_launch(void* const* d_in, const int* in_sizes, int n_in,
                   void* d_out, int out_size, void* d_ws, size_t ws_size,
                   hipStream_t stream) {
  (void)hipGetLastError();

  const float* Xsc   = (const float*)d_in[0];
  const float* Xbb   = (const float*)d_in[1];
  const float* attrs = (const float*)d_in[2];
  const int*  scE   = (const int*)d_in[3];
  const int*  bbE   = (const int*)d_in[4];
  const int*  rid   = (const int*)d_in[5];
  const float* scembW=(const float*)d_in[6];  const float* scembb=(const float*)d_in[7];
  const float* bbembW=(const float*)d_in[8];  const float* bbembb=(const float*)d_in[9];
  const float* resT  =(const float*)d_in[10];
  const float* rrW1  =(const float*)d_in[11]; const float* rrb1  =(const float*)d_in[12];
  const float* rrW2  =(const float*)d_in[13]; const float* rrb2  =(const float*)d_in[14];
  const float* scWl  =(const float*)d_in[15]; const float* scWr  =(const float*)d_in[16];
  const float* scWe  =(const float*)d_in[17]; const float* scAtt =(const float*)d_in[18];
  const float* scRes =(const float*)d_in[19]; const float* scBias=(const float*)d_in[20];
  const float* bbWl  =(const float*)d_in[21]; const float* bbWr  =(const float*)d_in[22];
  const float* bbAtt =(const float*)d_in[23]; const float* bbRes =(const float*)d_in[24];
  const float* bbBias=(const float*)d_in[25];
  const float* euW1  =(const float*)d_in[26]; const float* eub1  =(const float*)d_in[27];
  const float* eug   =(const float*)d_in[28]; const float* eube  =(const float*)d_in[29];
  const float* euW2  =(const float*)d_in[30]; const float* eub2  =(const float*)d_in[31];
  const float* bnuW  =(const float*)d_in[32]; const float* bnub  =(const float*)d_in[33];
  const float* bnug  =(const float*)d_in[34]; const float* bnube =(const float*)d_in[35];
  const float* afW   =(const float*)d_in[36]; const float* afb   =(const float*)d_in[37];
  const float* afg   =(const float*)d_in[38]; const float* afbe  =(const float*)d_in[39];
  const float* chiW  =(const float*)d_in[40]; const float* chib  =(const float*)d_in[41];
  const float* adW1  =(const float*)d_in[42]; const float* adW2  =(const float*)d_in[43];
  const float* vcW1  =(const float*)d_in[44]; const float* vcb1  =(const float*)d_in[45];
  const float* vcW2  =(const float*)d_in[46]; const float* vcb2  =(const float*)d_in[47];
  const float* bbhW1 =(const float*)d_in[48]; const float* bbhb1 =(const float*)d_in[49];
  const float* phiW2 =(const float*)d_in[50]; const float* psiW2 =(const float*)d_in[51];
  const float* xcaW2 =(const float*)d_in[52]; const float* xcab2 =(const float*)d_in[53];
  const float* vcbW2 =(const float*)d_in[54]; const float* vcbb2 =(const float*)d_in[55];
  float* out = (float*)d_out;

  // workspace: relTab (1 KiB) | floats | ints   (~54.1 MB)
  size_t need = 1024 + (size_t)(8*NN*64 + NE*8)*4 + (size_t)(2*(NN+1) + 2*NN + 2*NE)*4;
  if (ws_size < need){
    k_mark<<<(NN+255)/256, 256, 0, stream>>>(out);
    return;
  }
  float* relTab = (float*)d_ws;
  float* f = (float*)((char*)d_ws + 1024);
  float* sc    = f; f += NN*64;
  float* bbuf  = f; f += NN*64;
  float* xl_sc = f; f += NN*64;
  float* xr_sc = f; f += NN*64;
  float* bs_sc = f; f += NN*64;
  float* xl_bb = f; f += NN*64;
  float* xr_bb = f; f += NN*64;
  float* bs_bb = f; f += NN*64;
  float* ea    = f; f += NE*8;
  int* ip = (int*)f;
  int* rp_sc  = ip; ip += NN+1;
  int* rp_bb  = ip; ip += NN+1;
  int* cnt_sc = ip; ip += NN;
  int* cnt_bb = ip; ip += NN;
  int* ps_sc  = ip; ip += NE;
  int* ps_bb  = ip; ip += NE;

  k_init<<<(2*NN + 255)/256, 256, 0, stream>>>(cnt_sc, 2*NN);
  k_pre<<<12500, 256, 0, stream>>>(Xsc, Xbb, scembW, scembb, bbembW, bbembb,
                                   scE, bbE, sc, bbuf, cnt_sc, cnt_bb);
  k_scan<<<3, 256, 0, stream>>>(cnt_sc, cnt_bb, rp_sc, rp_bb,
                                resT, rrW1, rrb1, rrW2, rrb2, relTab);
  k_scatter<<<2500, 256, 0, stream>>>(scE, bbE, rid, relTab, attrs,
                                      cnt_sc, cnt_bb, ps_sc, ps_bb, ea);
  for (int l = 0; l < NL; l++){
    k_layer1<<<3750, 256, 0, stream>>>(ea, l,
        euW1, eub1, eug, eube, euW2, eub2,
        sc, bbuf,
        scWl, scWr, scRes, scBias,
        bbWl, bbWr, bbRes, bbBias,
        xl_sc, xr_sc, bs_sc, xl_bb, xr_bb, bs_bb);
    k_agg<<<10000, 256, 0, stream>>>(sc, bbuf, l,
        xl_sc, xr_sc, bs_sc, xl_bb, xr_bb, bs_bb,
        rp_sc, ps_sc, rp_bb, ps_bb,
        ea, scWe, scAtt, bbAtt);
  }
  k_heads<<<2500, 256, 0, stream>>>(sc, bbuf, rid,
      bnuW, bnub, bnug, bnube, afW, afb, afg, afbe,
      vcW1, vcb1, vcW2, vcb2,
      chiW, chib, adW1, adW2, bbhW1, bbhb1,
      phiW2, psiW2, xcaW2, xcab2, vcbW2, vcbb2, out);
}

// Round 7
// 1613.636 us; speedup vs baseline: 1.3962x; 1.0074x over previous
//
#include <hip/hip_runtime.h>
#include <hip/hip_bf16.h>

#define NN 20000
#define NE 320000
#define NL 12
#define BN_C 0.9999950000374997f

// Inputs/outputs are float32 on the wire (proven R5: dtype probe + pass at 1.5e-5).

// packed chi-count per residue (LETTERS='ARNDCQEGHILKMFPSTWYV'), 3 bits each;
// reference mask is prefix-structured: mask[res][i] = (i < nchi[res]).
#define CHI_PACK ( (0ull<<0)|(4ull<<3)|(2ull<<6)|(2ull<<9)|(1ull<<12)|(3ull<<15)|(3ull<<18)|(0ull<<21) \
                 | (2ull<<24)|(2ull<<27)|(2ull<<30)|(4ull<<33)|(3ull<<36)|(2ull<<39)|(0ull<<42)|(1ull<<45) \
                 | (1ull<<48)|(2ull<<51)|(2ull<<54)|(1ull<<57) )
__device__ __forceinline__ float chi_mask(int res, int i){
  int nchi = (int)((CHI_PACK >> (3*res)) & 7ull);
  return (i < nchi) ? 1.f : 0.f;
}

__device__ __forceinline__ float wsum(float v){
  #pragma unroll
  for (int off = 32; off > 0; off >>= 1) v += __shfl_xor(v, off);
  return v;
}

// ---------------- zero counters ----------------
__global__ __launch_bounds__(256) void k_init(int* p, int n){
  int i = blockIdx.x*256 + threadIdx.x;
  if (i < n) p[i] = 0;
}

// ---------------- ws-too-small marker ----------------
__global__ __launch_bounds__(256) void k_mark(float* out){
  int i = blockIdx.x*256 + threadIdx.x;
  if (i < NN) out[i] = 9.0f;
}

// ---------------- embeddings + degree histograms ----------------
// grid: [0,5000) sc embed, [5000,10000) bb embed, [10000,11250) sc hist, [11250,12500) bb hist
__global__ __launch_bounds__(256) void k_pre(
    const float* __restrict__ Xsc, const float* __restrict__ Xbb,
    const float* __restrict__ Wsc, const float* __restrict__ bsc,
    const float* __restrict__ Wbb, const float* __restrict__ bbb,
    const int* __restrict__ scE, const int* __restrict__ bbE,
    float* __restrict__ sc, float* __restrict__ bbuf, int* cnt_sc, int* cnt_bb){
  int b = blockIdx.x, t = threadIdx.x;
  if (b < 5000){
    int tid = b*256 + t;
    int node = tid >> 6, d = tid & 63;
    float acc = bsc[d];
    #pragma unroll
    for (int k = 0; k < 21; k++) acc += Xsc[node*21+k] * Wsc[k*64+d];
    sc[tid] = fmaxf(acc, 0.f);
  } else if (b < 10000){
    int tid = (b-5000)*256 + t;
    int node = tid >> 6, d = tid & 63;
    float acc = bbb[d];
    #pragma unroll
    for (int k = 0; k < 12; k++) acc += Xbb[node*12+k] * Wbb[k*64+d];
    bbuf[tid] = fmaxf(acc, 0.f);
  } else if (b < 11250){
    int e = (b-10000)*256 + t;
    atomicAdd(&cnt_sc[scE[NE + e]], 1);
  } else {
    int e = (b-11250)*256 + t;
    atomicAdd(&cnt_bb[bbE[NE + e]], 1);
  }
}

// ---------------- scan (blocks 0,1) + rel-gate table (block 2) ----------------
__global__ __launch_bounds__(256) void k_scan(
    int* cnt_sc, int* cnt_bb, int* rp_sc, int* rp_bb,
    const float* __restrict__ resT, const float* __restrict__ rrW1,
    const float* __restrict__ rrb1, const float* __restrict__ rrW2,
    const float* __restrict__ rrb2, float* relTab){
  int t = threadIdx.x;
  if (blockIdx.x == 2){
    __shared__ float sRT[320], sW1[512], sB1[16], sW2[16];
    for (int i = t; i < 320; i += 256) sRT[i] = resT[i];
    for (int i = t; i < 512; i += 256) sW1[i] = rrW1[i];
    if (t < 16){ sB1[t] = rrb1[t]; sW2[t] = rrW2[t]; }
    __syncthreads();
    float b2v = rrb2[0];
    for (int p = t; p < 400; p += 256){
      int a = p / 20, c = p % 20;
      const float* ra = &sRT[a*16];
      const float* rc = &sRT[c*16];
      float z = b2v;
      #pragma unroll
      for (int j = 0; j < 16; j++){
        float h = sB1[j];
        #pragma unroll
        for (int i = 0; i < 16; i++) h += ra[i] * sW1[i*16+j];
        #pragma unroll
        for (int i = 0; i < 16; i++) h += rc[i] * sW1[(16+i)*16+j];
        z += fmaxf(h, 0.f) * sW2[j];
      }
      relTab[p] = 1.f / (1.f + __expf(-z));
    }
    return;
  }
  int* cnt = blockIdx.x ? cnt_bb : cnt_sc;
  int* rp  = blockIdx.x ? rp_bb  : rp_sc;
  __shared__ int s[256];
  const int CH = 79;
  int beg = t * CH;
  int sum = 0;
  for (int i = beg; i < beg + CH && i < NN; i++) sum += cnt[i];
  s[t] = sum; __syncthreads();
  for (int off = 1; off < 256; off <<= 1){
    int v = (t >= off) ? s[t-off] : 0;
    __syncthreads();
    s[t] += v;
    __syncthreads();
  }
  int run = (t == 0) ? 0 : s[t-1];
  for (int i = beg; i < beg + CH && i < NN; i++){
    int c = cnt[i];
    rp[i] = run;
    cnt[i] = run;      // cursor for scatter
    run += c;
  }
  if (t == 0) rp[NN] = NE;
}

// ---------------- scatter: perm_src + gated sorted edge attrs ----------------
__global__ __launch_bounds__(256) void k_scatter(
    const int* __restrict__ scE, const int* __restrict__ bbE, const int* __restrict__ rid,
    const float* __restrict__ relTab, const float* __restrict__ attrs,
    int* cur_sc, int* cur_bb, int* __restrict__ ps_sc, int* __restrict__ ps_bb,
    float* __restrict__ ea){
  int b = blockIdx.x, t = threadIdx.x;
  if (b < 1250){
    int e = b*256 + t;
    int s = scE[e], d = scE[NE + e];
    float rel = relTab[rid[s]*20 + rid[d]];
    float4 A = ((const float4*)attrs)[e*2];
    float4 B = ((const float4*)attrs)[e*2+1];
    A.x *= rel; A.y *= rel; A.z *= rel; A.w *= rel;
    B.x *= rel; B.y *= rel; B.z *= rel; B.w *= rel;
    int pos = atomicAdd(&cur_sc[d], 1);
    ps_sc[pos] = s;
    ((float4*)ea)[pos*2]   = A;
    ((float4*)ea)[pos*2+1] = B;
  } else {
    int e = (b-1250)*256 + t;
    int s = bbE[e], d = bbE[NE + e];
    int pos = atomicAdd(&cur_bb[d], 1);
    ps_bb[pos] = s;
  }
}

// ---------------- per-node matmuls ----------------
__device__ void node_mm(float* sx, const float* __restrict__ x,
                        const float* __restrict__ Wl, const float* __restrict__ Wr,
                        const float* __restrict__ Wres, const float* __restrict__ bias, int l,
                        float* __restrict__ xl, float* __restrict__ xr, float* __restrict__ base,
                        int tile){
  int t = threadIdx.x;
  for (int i = t; i < 1024; i += 256) sx[i] = x[tile*1024 + i];
  __syncthreads();
  int d = t & 63, r = t >> 6;
  int wo = l*4096 + d;
  float aL[4] = {0,0,0,0}, aR[4] = {0,0,0,0}, aB[4];
  float bv = bias[l*64 + d];
  #pragma unroll
  for (int j = 0; j < 4; j++) aB[j] = bv;
  #pragma unroll 4
  for (int k = 0; k < 64; k++){
    float wl = Wl[wo + k*64], wr = Wr[wo + k*64], ws = Wres[wo + k*64];
    #pragma unroll
    for (int j = 0; j < 4; j++){
      float xv = sx[(r + 4*j)*64 + k];
      aL[j] += xv*wl; aR[j] += xv*wr; aB[j] += xv*ws;
    }
  }
  int n0 = tile*16 + r;
  #pragma unroll
  for (int j = 0; j < 4; j++){
    int n = n0 + 4*j;
    xl[n*64+d] = aL[j]; xr[n*64+d] = aR[j]; base[n*64+d] = aB[j];
  }
}

// grid roles: [0,1250) edge update, [1250,2500) sc node mm, [2500,3750) bb node mm
__global__ __launch_bounds__(256) void k_layer1(
    float* __restrict__ ea, int l,
    const float* __restrict__ euW1, const float* __restrict__ eub1,
    const float* __restrict__ eug, const float* __restrict__ eube,
    const float* __restrict__ euW2, const float* __restrict__ eub2,
    const float* __restrict__ sc, const float* __restrict__ bbv,
    const float* __restrict__ scWl, const float* __restrict__ scWr,
    const float* __restrict__ scRes, const float* __restrict__ scBias,
    const float* __restrict__ bbWl, const float* __restrict__ bbWr,
    const float* __restrict__ bbRes, const float* __restrict__ bbBias,
    float* __restrict__ xl_sc, float* __restrict__ xr_sc, float* __restrict__ bs_sc,
    float* __restrict__ xl_bb, float* __restrict__ xr_bb, float* __restrict__ bs_bb){
  __shared__ float smem[1024];
  int b = blockIdx.x, t = threadIdx.x;
  if (b < 1250){
    float* sW1 = smem;        float* sB1 = smem+128; float* sG  = smem+144;
    float* sBe = smem+160;    float* sW2 = smem+176; float* sB2 = smem+304;
    for (int i = t; i < 128; i += 256){ sW1[i] = euW1[l*128+i]; sW2[i] = euW2[l*128+i]; }
    if (t < 16){ sB1[t] = eub1[l*16+t]; sG[t] = eug[l*16+t]; sBe[t] = eube[l*16+t]; }
    if (t < 8) sB2[t] = eub2[l*8+t];
    __syncthreads();
    int e = b*256 + t;
    float4 A = ((const float4*)ea)[e*2];
    float4 B = ((const float4*)ea)[e*2+1];
    float a[8] = {A.x,A.y,A.z,A.w,B.x,B.y,B.z,B.w};
    float h[16];
    #pragma unroll
    for (int j = 0; j < 16; j++){
      float v = sB1[j];
      #pragma unroll
      for (int i = 0; i < 8; i++) v += a[i] * sW1[i*16+j];
      h[j] = fmaxf(v*BN_C*sG[j] + sBe[j], 0.f);
    }
    #pragma unroll
    for (int i = 0; i < 8; i++){
      float v = sB2[i] + a[i];
      #pragma unroll
      for (int j = 0; j < 16; j++) v += h[j] * sW2[j*8+i];
      a[i] = v;
    }
    ((float4*)ea)[e*2]   = make_float4(a[0],a[1],a[2],a[3]);
    ((float4*)ea)[e*2+1] = make_float4(a[4],a[5],a[6],a[7]);
  } else if (b < 2500){
    node_mm(smem, sc, scWl, scWr, scRes, scBias, l, xl_sc, xr_sc, bs_sc, b-1250);
  } else {
    node_mm(smem, bbv, bbWl, bbWr, bbRes, bbBias, l, xl_bb, xr_bb, bs_bb, b-2500);
  }
}

// ---------------- GAT aggregation: wave/node, plain-exp softmax, unroll x4 ----------------
// Max-tracking dropped: logits are bounded (|e| ~ O(10) << 88) so exp(e) is safe
// and exp(e)/sum(exp(e)) is mathematically identical to the max-subtracted form.
// grid: [0,5000) sc graph, [5000,10000) bb graph; 4 waves/block
__global__ __launch_bounds__(256) void k_agg(
    float* __restrict__ sc, float* __restrict__ bbv, int l,
    const float* __restrict__ xl_sc, const float* __restrict__ xr_sc, const float* __restrict__ bs_sc,
    const float* __restrict__ xl_bb, const float* __restrict__ xr_bb, const float* __restrict__ bs_bb,
    const int* __restrict__ rp_sc, const int* __restrict__ ps_sc,
    const int* __restrict__ rp_bb, const int* __restrict__ ps_bb,
    const float* __restrict__ ea, const float* __restrict__ We,
    const float* __restrict__ scAtt, const float* __restrict__ bbAtt){
  int b = blockIdx.x;
  int lane = threadIdx.x & 63, wid = threadIdx.x >> 6;
  bool is_sc = b < 5000;
  int n = (is_sc ? b : b - 5000)*4 + wid;
  const float* xl = is_sc ? xl_sc : xl_bb;
  const float* xr = is_sc ? xr_sc : xr_bb;
  const float* bs = is_sc ? bs_sc : bs_bb;
  const int* rp = is_sc ? rp_sc : rp_bb;
  const int* ps = is_sc ? ps_sc : ps_bb;
  float attv = is_sc ? scAtt[l*64+lane] : bbAtt[l*64+lane];
  float w0=0,w1=0,w2=0,w3=0,w4=0,w5=0,w6=0,w7=0;
  if (is_sc){
    int o = l*512 + lane;
    w0=We[o]; w1=We[o+64]; w2=We[o+128]; w3=We[o+192];
    w4=We[o+256]; w5=We[o+320]; w6=We[o+384]; w7=We[o+448];
  }
  int beg = rp[n], end = rp[n+1];
  float xrv = xr[n*64+lane];
  float o = 0.f, s = 0.f;
  int last = end - 1;
  for (int eid = beg; eid < end; eid += 4){
    int i1 = min(eid+1, last), i2 = min(eid+2, last), i3 = min(eid+3, last);
    bool k1 = eid+1 < end, k2 = eid+2 < end, k3 = eid+3 < end;
    int sn0 = ps[eid], sn1 = ps[i1], sn2 = ps[i2], sn3 = ps[i3];
    float v0 = xl[sn0*64+lane];
    float v1 = xl[sn1*64+lane];
    float v2 = xl[sn2*64+lane];
    float v3 = xl[sn3*64+lane];
    float m0 = v0 + xrv, m1 = v1 + xrv, m2 = v2 + xrv, m3 = v3 + xrv;
    if (is_sc){
      const float4* a0 = (const float4*)(ea + (size_t)eid*8);
      const float4* a1 = (const float4*)(ea + (size_t)i1*8);
      const float4* a2 = (const float4*)(ea + (size_t)i2*8);
      const float4* a3 = (const float4*)(ea + (size_t)i3*8);
      float4 A, B;
      A = a0[0]; B = a0[1];
      m0 += A.x*w0 + A.y*w1 + A.z*w2 + A.w*w3 + B.x*w4 + B.y*w5 + B.z*w6 + B.w*w7;
      A = a1[0]; B = a1[1];
      m1 += A.x*w0 + A.y*w1 + A.z*w2 + A.w*w3 + B.x*w4 + B.y*w5 + B.z*w6 + B.w*w7;
      A = a2[0]; B = a2[1];
      m2 += A.x*w0 + A.y*w1 + A.z*w2 + A.w*w3 + B.x*w4 + B.y*w5 + B.z*w6 + B.w*w7;
      A = a3[0]; B = a3[1];
      m3 += A.x*w0 + A.y*w1 + A.z*w2 + A.w*w3 + B.x*w4 + B.y*w5 + B.z*w6 + B.w*w7;
    }
    float e0 = (fmaxf(m0, 0.f) + 0.2f*fminf(m0, 0.f)) * attv;
    float e1 = (fmaxf(m1, 0.f) + 0.2f*fminf(m1, 0.f)) * attv;
    float e2 = (fmaxf(m2, 0.f) + 0.2f*fminf(m2, 0.f)) * attv;
    float e3 = (fmaxf(m3, 0.f) + 0.2f*fminf(m3, 0.f)) * attv;
    #pragma unroll
    for (int off = 32; off > 0; off >>= 1){
      e0 += __shfl_xor(e0, off);
      e1 += __shfl_xor(e1, off);
      e2 += __shfl_xor(e2, off);
      e3 += __shfl_xor(e3, off);
    }
    float p0 = __expf(e0);
    float p1 = k1 ? __expf(e1) : 0.f;
    float p2 = k2 ? __expf(e2) : 0.f;
    float p3 = k3 ? __expf(e3) : 0.f;
    o += p0*v0 + p1*v1 + p2*v2 + p3*v3;
    s += p0 + p1 + p2 + p3;
  }
  float* outp = is_sc ? sc : bbv;
  outp[n*64+lane] = o/(s + 1e-16f) + bs[n*64+lane];
}

// ---------------- heads: chi (sc) | fusion + v_com + backbone heads (bb) ----------------
// grid: [0,1250) chi, [1250,2500) fusion+bb heads
__global__ __launch_bounds__(256) void k_heads(
    const float* __restrict__ sc, const float* __restrict__ bbv, const int* __restrict__ rid,
    const float* __restrict__ bnuW, const float* __restrict__ bnub,
    const float* __restrict__ bnug, const float* __restrict__ bnube,
    const float* __restrict__ afW, const float* __restrict__ afb,
    const float* __restrict__ afg, const float* __restrict__ afbe,
    const float* __restrict__ vcW1, const float* __restrict__ vcb1,
    const float* __restrict__ vcW2, const float* __restrict__ vcb2,
    const float* __restrict__ chiW, const float* __restrict__ chib,
    const float* __restrict__ adW1, const float* __restrict__ adW2,
    const float* __restrict__ bbhW1, const float* __restrict__ bbhb1,
    const float* __restrict__ phiW2, const float* __restrict__ psiW2,
    const float* __restrict__ xcaW2, const float* __restrict__ xcab2,
    const float* __restrict__ vcbW2, const float* __restrict__ vcbb2,
    float* __restrict__ out){
  __shared__ float sx[1024];
  __shared__ float sh[1024];
  __shared__ int srid[16];
  int b = blockIdx.x, t = threadIdx.x;
  int d = t & 63, r = t >> 6;
  if (b < 1250){
    int tile = b;
    for (int i = t; i < 1024; i += 256) sx[i] = sc[tile*1024 + i];
    if (t < 16) srid[t] = rid[tile*16 + t];
    __syncthreads();
    for (int i = 0; i < 4; i++){
      const float* W = chiW + i*4096;
      float acc[4] = {0,0,0,0};
      #pragma unroll 4
      for (int k = 0; k < 64; k++){
        float w = W[k*64+d];
        #pragma unroll
        for (int j = 0; j < 4; j++) acc[j] += sx[(r + 4*j)*64 + k] * w;
      }
      float bi = chib[i*64+d];
      #pragma unroll
      for (int j = 0; j < 4; j++){
        float mk = chi_mask(srid[r + 4*j], i);
        sh[(r + 4*j)*64 + d] = fmaxf(acc[j] + bi, 0.f) * mk;
      }
      __syncthreads();
      float a2[4] = {0,0,0,0};
      #pragma unroll 4
      for (int k = 0; k < 64; k++){
        float w = adW1[k*64+d];
        #pragma unroll
        for (int j = 0; j < 4; j++) a2[j] += sh[(r + 4*j)*64 + k] * w;
      }
      float w2 = adW2[d];
      #pragma unroll
      for (int j = 0; j < 4; j++){
        float p = wsum(fmaxf(a2[j], 0.f) * w2);
        if (d == 0) out[i*NN + tile*16 + r + 4*j] = p;
      }
      __syncthreads();
    }
  } else {
    int tile = b - 1250;
    for (int i = t; i < 1024; i += 256){ sx[i] = sc[tile*1024 + i]; sh[i] = bbv[tile*1024 + i]; }
    __syncthreads();
    float aU[4] = {0,0,0,0}, aV[4] = {0,0,0,0};
    #pragma unroll 4
    for (int k = 0; k < 64; k++){
      float wu = bnuW[k*64+d], wv = vcW1[k*64+d];
      #pragma unroll
      for (int j = 0; j < 4; j++){
        float xv = sx[(r + 4*j)*64 + k];
        aU[j] += xv*wu; aV[j] += xv*wv;
      }
    }
    float afwd = afW[d];
    float bnubd = bnub[d], bnugd = bnug[d], bnubed = bnube[d];
    float vcb1d = vcb1[d];
    float afbv = afb[0], afgv = afg[0], afbev = afbe[0];
    #pragma unroll
    for (int j = 0; j < 4; j++){
      int node = tile*16 + r + 4*j;
      float z = wsum(sx[(r + 4*j)*64 + d] * afwd);
      float attn = 1.f / (1.f + __expf(-((z + afbv)*BN_C*afgv + afbev)));
      float u = fmaxf((aU[j] + bnubd)*BN_C*bnugd + bnubed, 0.f);
      sh[(r + 4*j)*64 + d] += attn*u;
      float vh = fmaxf(aV[j] + vcb1d, 0.f);
      #pragma unroll
      for (int c = 0; c < 3; c++){
        float p = wsum(vh * vcW2[d*3+c]);
        if (d == 0) out[4*NN + node*3 + c] = p + vcb2[c];
      }
    }
    __syncthreads();
    for (int i = 0; i < 4; i++){
      const float* W = bbhW1 + i*4096;
      float acc[4] = {0,0,0,0};
      #pragma unroll 4
      for (int k = 0; k < 64; k++){
        float w = W[k*64+d];
        #pragma unroll
        for (int j = 0; j < 4; j++) acc[j] += sh[(r + 4*j)*64 + k] * w;
      }
      float bi = bbhb1[i*64+d];
      if (i < 2){
        float w2 = (i == 0) ? phiW2[d] : psiW2[d];
        #pragma unroll
        for (int j = 0; j < 4; j++){
          float p = wsum(fmaxf(acc[j] + bi, 0.f) * w2);
          if (d == 0) out[(7+i)*NN + tile*16 + r + 4*j] = p;
        }
      } else {
        const float* W2 = (i == 2) ? xcaW2 : vcbW2;
        const float* B2 = (i == 2) ? xcab2 : vcbb2;
        int off = (i == 2) ? 9*NN : 12*NN;
        #pragma unroll
        for (int j = 0; j < 4; j++){
          float h = fmaxf(acc[j] + bi, 0.f);
          #pragma unroll
          for (int c = 0; c < 3; c++){
            float p = wsum(h * W2[d*3+c]);
            if (d == 0) out[off + (tile*16 + r + 4*j)*3 + c] = p + B2[c];
          }
        }
      }
    }
  }
}

extern "C" __attribute__((visibility("default")))
void kernel_launch(void* const* d_in, const int* in_sizes, int n_in,
                   void* d_out, int out_size, void* d_ws, size_t ws_size,
                   hipStream_t stream) {
  (void)hipGetLastError();

  const float* Xsc   = (const float*)d_in[0];
  const float* Xbb   = (const float*)d_in[1];
  const float* attrs = (const float*)d_in[2];
  const int*  scE   = (const int*)d_in[3];
  const int*  bbE   = (const int*)d_in[4];
  const int*  rid   = (const int*)d_in[5];
  const float* scembW=(const float*)d_in[6];  const float* scembb=(const float*)d_in[7];
  const float* bbembW=(const float*)d_in[8];  const float* bbembb=(const float*)d_in[9];
  const float* resT  =(const float*)d_in[10];
  const float* rrW1  =(const float*)d_in[11]; const float* rrb1  =(const float*)d_in[12];
  const float* rrW2  =(const float*)d_in[13]; const float* rrb2  =(const float*)d_in[14];
  const float* scWl  =(const float*)d_in[15]; const float* scWr  =(const float*)d_in[16];
  const float* scWe  =(const float*)d_in[17]; const float* scAtt =(const float*)d_in[18];
  const float* scRes =(const float*)d_in[19]; const float* scBias=(const float*)d_in[20];
  const float* bbWl  =(const float*)d_in[21]; const float* bbWr  =(const float*)d_in[22];
  const float* bbAtt =(const float*)d_in[23]; const float* bbRes =(const float*)d_in[24];
  const float* bbBias=(const float*)d_in[25];
  const float* euW1  =(const float*)d_in[26]; const float* eub1  =(const float*)d_in[27];
  const float* eug   =(const float*)d_in[28]; const float* eube  =(const float*)d_in[29];
  const float* euW2  =(const float*)d_in[30]; const float* eub2  =(const float*)d_in[31];
  const float* bnuW  =(const float*)d_in[32]; const float* bnub  =(const float*)d_in[33];
  const float* bnug  =(const float*)d_in[34]; const float* bnube =(const float*)d_in[35];
  const float* afW   =(const float*)d_in[36]; const float* afb   =(const float*)d_in[37];
  const float* afg   =(const float*)d_in[38]; const float* afbe  =(const float*)d_in[39];
  const float* chiW  =(const float*)d_in[40]; const float* chib  =(const float*)d_in[41];
  const float* adW1  =(const float*)d_in[42]; const float* adW2  =(const float*)d_in[43];
  const float* vcW1  =(const float*)d_in[44]; const float* vcb1  =(const float*)d_in[45];
  const float* vcW2  =(const float*)d_in[46]; const float* vcb2  =(const float*)d_in[47];
  const float* bbhW1 =(const float*)d_in[48]; const float* bbhb1 =(const float*)d_in[49];
  const float* phiW2 =(const float*)d_in[50]; const float* psiW2 =(const float*)d_in[51];
  const float* xcaW2 =(const float*)d_in[52]; const float* xcab2 =(const float*)d_in[53];
  const float* vcbW2 =(const float*)d_in[54]; const float* vcbb2 =(const float*)d_in[55];
  float* out = (float*)d_out;

  size_t need = 1024 + (size_t)(8*NN*64 + NE*8)*4 + (size_t)(2*(NN+1) + 2*NN + 2*NE)*4;
  if (ws_size < need){
    k_mark<<<(NN+255)/256, 256, 0, stream>>>(out);
    return;
  }
  float* relTab = (float*)d_ws;
  float* f = (float*)((char*)d_ws + 1024);
  float* sc    = f; f += NN*64;
  float* bbuf  = f; f += NN*64;
  float* xl_sc = f; f += NN*64;
  float* xr_sc = f; f += NN*64;
  float* bs_sc = f; f += NN*64;
  float* xl_bb = f; f += NN*64;
  float* xr_bb = f; f += NN*64;
  float* bs_bb = f; f += NN*64;
  float* ea    = f; f += NE*8;
  int* ip = (int*)f;
  int* rp_sc  = ip; ip += NN+1;
  int* rp_bb  = ip; ip += NN+1;
  int* cnt_sc = ip; ip += NN;
  int* cnt_bb = ip; ip += NN;
  int* ps_sc  = ip; ip += NE;
  int* ps_bb  = ip; ip += NE;

  k_init<<<(2*NN + 255)/256, 256, 0, stream>>>(cnt_sc, 2*NN);
  k_pre<<<12500, 256, 0, stream>>>(Xsc, Xbb, scembW, scembb, bbembW, bbembb,
                                   scE, bbE, sc, bbuf, cnt_sc, cnt_bb);
  k_scan<<<3, 256, 0, stream>>>(cnt_sc, cnt_bb, rp_sc, rp_bb,
                                resT, rrW1, rrb1, rrW2, rrb2, relTab);
  k_scatter<<<2500, 256, 0, stream>>>(scE, bbE, rid, relTab, attrs,
                                      cnt_sc, cnt_bb, ps_sc, ps_bb, ea);
  for (int l = 0; l < NL; l++){
    k_layer1<<<3750, 256, 0, stream>>>(ea, l,
        euW1, eub1, eug, eube, euW2, eub2,
        sc, bbuf,
        scWl, scWr, scRes, scBias,
        bbWl, bbWr, bbRes, bbBias,
        xl_sc, xr_sc, bs_sc, xl_bb, xr_bb, bs_bb);
    k_agg<<<10000, 256, 0, stream>>>(sc, bbuf, l,
        xl_sc, xr_sc, bs_sc, xl_bb, xr_bb, bs_bb,
        rp_sc, ps_sc, rp_bb, ps_bb,
        ea, scWe, scAtt, bbAtt);
  }
  k_heads<<<2500, 256, 0, stream>>>(sc, bbuf, rid,
      bnuW, bnub, bnug, bnube, afW, afb, afg, afbe,
      vcW1, vcb1, vcW2, vcb2,
      chiW, chib, adW1, adW2, bbhW1, bbhb1,
      phiW2, psiW2, xcaW2, xcab2, vcbW2, vcbb2, out);
}

// Round 8
// 1502.420 us; speedup vs baseline: 1.4996x; 1.0740x over previous
//
#include <hip/hip_runtime.h>
#include <hip/hip_bf16.h>

#define NN 20000
#define NE 320000
#define NL 12
#define BN_C 0.9999950000374997f

// Inputs/outputs are float32 on the wire (proven R5: dtype probe + pass at 1.5e-5).

// packed chi-count per residue (LETTERS='ARNDCQEGHILKMFPSTWYV'), 3 bits each;
// reference mask is prefix-structured: mask[res][i] = (i < nchi[res]).
#define CHI_PACK ( (0ull<<0)|(4ull<<3)|(2ull<<6)|(2ull<<9)|(1ull<<12)|(3ull<<15)|(3ull<<18)|(0ull<<21) \
                 | (2ull<<24)|(2ull<<27)|(2ull<<30)|(4ull<<33)|(3ull<<36)|(2ull<<39)|(0ull<<42)|(1ull<<45) \
                 | (1ull<<48)|(2ull<<51)|(2ull<<54)|(1ull<<57) )
__device__ __forceinline__ float chi_mask(int res, int i){
  int nchi = (int)((CHI_PACK >> (3*res)) & 7ull);
  return (i < nchi) ? 1.f : 0.f;
}

__device__ __forceinline__ float wsum(float v){
  #pragma unroll
  for (int off = 32; off > 0; off >>= 1) v += __shfl_xor(v, off);
  return v;
}
__device__ __forceinline__ float leaky(float x){
  return fmaxf(x, 0.f) + 0.2f*fminf(x, 0.f);
}

// ---------------- zero counters ----------------
__global__ __launch_bounds__(256) void k_init(int* p, int n){
  int i = blockIdx.x*256 + threadIdx.x;
  if (i < n) p[i] = 0;
}

// ---------------- ws-too-small marker ----------------
__global__ __launch_bounds__(256) void k_mark(float* out){
  int i = blockIdx.x*256 + threadIdx.x;
  if (i < NN) out[i] = 9.0f;
}

// ---------------- embeddings + degree histograms ----------------
// grid: [0,5000) sc embed, [5000,10000) bb embed, [10000,11250) sc hist, [11250,12500) bb hist
__global__ __launch_bounds__(256) void k_pre(
    const float* __restrict__ Xsc, const float* __restrict__ Xbb,
    const float* __restrict__ Wsc, const float* __restrict__ bsc,
    const float* __restrict__ Wbb, const float* __restrict__ bbb,
    const int* __restrict__ scE, const int* __restrict__ bbE,
    float* __restrict__ sc, float* __restrict__ bbuf, int* cnt_sc, int* cnt_bb){
  int b = blockIdx.x, t = threadIdx.x;
  if (b < 5000){
    int tid = b*256 + t;
    int node = tid >> 6, d = tid & 63;
    float acc = bsc[d];
    #pragma unroll
    for (int k = 0; k < 21; k++) acc += Xsc[node*21+k] * Wsc[k*64+d];
    sc[tid] = fmaxf(acc, 0.f);
  } else if (b < 10000){
    int tid = (b-5000)*256 + t;
    int node = tid >> 6, d = tid & 63;
    float acc = bbb[d];
    #pragma unroll
    for (int k = 0; k < 12; k++) acc += Xbb[node*12+k] * Wbb[k*64+d];
    bbuf[tid] = fmaxf(acc, 0.f);
  } else if (b < 11250){
    int e = (b-10000)*256 + t;
    atomicAdd(&cnt_sc[scE[NE + e]], 1);
  } else {
    int e = (b-11250)*256 + t;
    atomicAdd(&cnt_bb[bbE[NE + e]], 1);
  }
}

// ---------------- scan (blocks 0,1) + rel-gate table (block 2) ----------------
__global__ __launch_bounds__(256) void k_scan(
    int* cnt_sc, int* cnt_bb, int* rp_sc, int* rp_bb,
    const float* __restrict__ resT, const float* __restrict__ rrW1,
    const float* __restrict__ rrb1, const float* __restrict__ rrW2,
    const float* __restrict__ rrb2, float* relTab){
  int t = threadIdx.x;
  if (blockIdx.x == 2){
    __shared__ float sRT[320], sW1[512], sB1[16], sW2[16];
    for (int i = t; i < 320; i += 256) sRT[i] = resT[i];
    for (int i = t; i < 512; i += 256) sW1[i] = rrW1[i];
    if (t < 16){ sB1[t] = rrb1[t]; sW2[t] = rrW2[t]; }
    __syncthreads();
    float b2v = rrb2[0];
    for (int p = t; p < 400; p += 256){
      int a = p / 20, c = p % 20;
      const float* ra = &sRT[a*16];
      const float* rc = &sRT[c*16];
      float z = b2v;
      #pragma unroll
      for (int j = 0; j < 16; j++){
        float h = sB1[j];
        #pragma unroll
        for (int i = 0; i < 16; i++) h += ra[i] * sW1[i*16+j];
        #pragma unroll
        for (int i = 0; i < 16; i++) h += rc[i] * sW1[(16+i)*16+j];
        z += fmaxf(h, 0.f) * sW2[j];
      }
      relTab[p] = 1.f / (1.f + __expf(-z));
    }
    return;
  }
  int* cnt = blockIdx.x ? cnt_bb : cnt_sc;
  int* rp  = blockIdx.x ? rp_bb  : rp_sc;
  __shared__ int s[256];
  const int CH = 79;
  int beg = t * CH;
  int sum = 0;
  for (int i = beg; i < beg + CH && i < NN; i++) sum += cnt[i];
  s[t] = sum; __syncthreads();
  for (int off = 1; off < 256; off <<= 1){
    int v = (t >= off) ? s[t-off] : 0;
    __syncthreads();
    s[t] += v;
    __syncthreads();
  }
  int run = (t == 0) ? 0 : s[t-1];
  for (int i = beg; i < beg + CH && i < NN; i++){
    int c = cnt[i];
    rp[i] = run;
    cnt[i] = run;      // cursor for scatter
    run += c;
  }
  if (t == 0) rp[NN] = NE;
}

// ---------------- scatter: perm_src + gated sorted edge attrs ----------------
__global__ __launch_bounds__(256) void k_scatter(
    const int* __restrict__ scE, const int* __restrict__ bbE, const int* __restrict__ rid,
    const float* __restrict__ relTab, const float* __restrict__ attrs,
    int* cur_sc, int* cur_bb, int* __restrict__ ps_sc, int* __restrict__ ps_bb,
    float* __restrict__ ea){
  int b = blockIdx.x, t = threadIdx.x;
  if (b < 1250){
    int e = b*256 + t;
    int s = scE[e], d = scE[NE + e];
    float rel = relTab[rid[s]*20 + rid[d]];
    float4 A = ((const float4*)attrs)[e*2];
    float4 B = ((const float4*)attrs)[e*2+1];
    A.x *= rel; A.y *= rel; A.z *= rel; A.w *= rel;
    B.x *= rel; B.y *= rel; B.z *= rel; B.w *= rel;
    int pos = atomicAdd(&cur_sc[d], 1);
    ps_sc[pos] = s;
    ((float4*)ea)[pos*2]   = A;
    ((float4*)ea)[pos*2+1] = B;
  } else {
    int e = (b-1250)*256 + t;
    int s = bbE[e], d = bbE[NE + e];
    int pos = atomicAdd(&cur_bb[d], 1);
    ps_bb[pos] = s;
  }
}

// ---------------- per-node matmuls ----------------
__device__ void node_mm(float* sx, const float* __restrict__ x,
                        const float* __restrict__ Wl, const float* __restrict__ Wr,
                        const float* __restrict__ Wres, const float* __restrict__ bias, int l,
                        float* __restrict__ xl, float* __restrict__ xr, float* __restrict__ base,
                        int tile){
  int t = threadIdx.x;
  for (int i = t; i < 1024; i += 256) sx[i] = x[tile*1024 + i];
  __syncthreads();
  int d = t & 63, r = t >> 6;
  int wo = l*4096 + d;
  float aL[4] = {0,0,0,0}, aR[4] = {0,0,0,0}, aB[4];
  float bv = bias[l*64 + d];
  #pragma unroll
  for (int j = 0; j < 4; j++) aB[j] = bv;
  #pragma unroll 4
  for (int k = 0; k < 64; k++){
    float wl = Wl[wo + k*64], wr = Wr[wo + k*64], ws = Wres[wo + k*64];
    #pragma unroll
    for (int j = 0; j < 4; j++){
      float xv = sx[(r + 4*j)*64 + k];
      aL[j] += xv*wl; aR[j] += xv*wr; aB[j] += xv*ws;
    }
  }
  int n0 = tile*16 + r;
  #pragma unroll
  for (int j = 0; j < 4; j++){
    int n = n0 + 4*j;
    xl[n*64+d] = aL[j]; xr[n*64+d] = aR[j]; base[n*64+d] = aB[j];
  }
}

// grid roles: [0,1250) edge update, [1250,2500) sc node mm, [2500,3750) bb node mm
__global__ __launch_bounds__(256) void k_layer1(
    float* __restrict__ ea, int l,
    const float* __restrict__ euW1, const float* __restrict__ eub1,
    const float* __restrict__ eug, const float* __restrict__ eube,
    const float* __restrict__ euW2, const float* __restrict__ eub2,
    const float* __restrict__ sc, const float* __restrict__ bbv,
    const float* __restrict__ scWl, const float* __restrict__ scWr,
    const float* __restrict__ scRes, const float* __restrict__ scBias,
    const float* __restrict__ bbWl, const float* __restrict__ bbWr,
    const float* __restrict__ bbRes, const float* __restrict__ bbBias,
    float* __restrict__ xl_sc, float* __restrict__ xr_sc, float* __restrict__ bs_sc,
    float* __restrict__ xl_bb, float* __restrict__ xr_bb, float* __restrict__ bs_bb){
  __shared__ float smem[1024];
  int b = blockIdx.x, t = threadIdx.x;
  if (b < 1250){
    float* sW1 = smem;        float* sB1 = smem+128; float* sG  = smem+144;
    float* sBe = smem+160;    float* sW2 = smem+176; float* sB2 = smem+304;
    for (int i = t; i < 128; i += 256){ sW1[i] = euW1[l*128+i]; sW2[i] = euW2[l*128+i]; }
    if (t < 16){ sB1[t] = eub1[l*16+t]; sG[t] = eug[l*16+t]; sBe[t] = eube[l*16+t]; }
    if (t < 8) sB2[t] = eub2[l*8+t];
    __syncthreads();
    int e = b*256 + t;
    float4 A = ((const float4*)ea)[e*2];
    float4 B = ((const float4*)ea)[e*2+1];
    float a[8] = {A.x,A.y,A.z,A.w,B.x,B.y,B.z,B.w};
    float h[16];
    #pragma unroll
    for (int j = 0; j < 16; j++){
      float v = sB1[j];
      #pragma unroll
      for (int i = 0; i < 8; i++) v += a[i] * sW1[i*16+j];
      h[j] = fmaxf(v*BN_C*sG[j] + sBe[j], 0.f);
    }
    #pragma unroll
    for (int i = 0; i < 8; i++){
      float v = sB2[i] + a[i];
      #pragma unroll
      for (int j = 0; j < 16; j++) v += h[j] * sW2[j*8+i];
      a[i] = v;
    }
    ((float4*)ea)[e*2]   = make_float4(a[0],a[1],a[2],a[3]);
    ((float4*)ea)[e*2+1] = make_float4(a[4],a[5],a[6],a[7]);
  } else if (b < 2500){
    node_mm(smem, sc, scWl, scWr, scRes, scBias, l, xl_sc, xr_sc, bs_sc, b-1250);
  } else {
    node_mm(smem, bbv, bbWl, bbWr, bbRes, bbBias, l, xl_bb, xr_bb, bs_bb, b-2500);
  }
}

// ---------------- GAT aggregation: HALF-WAVE per edge, float2 dims ----------------
// Each 32-lane half-wave owns one edge; lane l2 holds dims {2*l2, 2*l2+1}.
// Butterfly is 5 stages (within half), one wave instr advances 2 edges.
// Plain-exp softmax (logits bounded, proven R7). 2 pairs (4 edges) in flight.
// grid: [0,5000) sc graph, [5000,10000) bb graph; 4 waves/block
__global__ __launch_bounds__(256) void k_agg(
    float* __restrict__ sc, float* __restrict__ bbv, int l,
    const float* __restrict__ xl_sc, const float* __restrict__ xr_sc, const float* __restrict__ bs_sc,
    const float* __restrict__ xl_bb, const float* __restrict__ xr_bb, const float* __restrict__ bs_bb,
    const int* __restrict__ rp_sc, const int* __restrict__ ps_sc,
    const int* __restrict__ rp_bb, const int* __restrict__ ps_bb,
    const float* __restrict__ ea, const float* __restrict__ We,
    const float* __restrict__ scAtt, const float* __restrict__ bbAtt){
  int b = blockIdx.x;
  int lane = threadIdx.x & 63, wid = threadIdx.x >> 6;
  int half = lane >> 5, l2 = lane & 31;
  bool is_sc = b < 5000;
  int n = (is_sc ? b : b - 5000)*4 + wid;
  const float* xl = is_sc ? xl_sc : xl_bb;
  const float* xr = is_sc ? xr_sc : xr_bb;
  const float* bs = is_sc ? bs_sc : bs_bb;
  const int* rp = is_sc ? rp_sc : rp_bb;
  const int* ps = is_sc ? ps_sc : ps_bb;
  const float2* xl2 = (const float2*)xl;
  float2 att2 = ((const float2*)((is_sc ? scAtt : bbAtt) + l*64))[l2];
  float2 w[8];
  if (is_sc){
    #pragma unroll
    for (int j = 0; j < 8; j++) w[j] = ((const float2*)(We + l*512 + j*64))[l2];
  }
  int beg = rp[n], end = rp[n+1];
  int last = end - 1;
  float2 xr2 = ((const float2*)xr)[n*32 + l2];
  float ox = 0.f, oy = 0.f, s = 0.f;
  for (int eid = beg; eid < end; eid += 4){
    int ia = eid + half;       bool va = ia < end; ia = min(ia, last);
    int ib = eid + 2 + half;   bool vb = ib < end; ib = min(ib, last);
    int sna = ps[ia], snb = ps[ib];
    float2 vA = xl2[sna*32 + l2];
    float2 vB = xl2[snb*32 + l2];
    float mAx = vA.x + xr2.x, mAy = vA.y + xr2.y;
    float mBx = vB.x + xr2.x, mBy = vB.y + xr2.y;
    if (is_sc){
      const float4* pa4 = (const float4*)(ea + (size_t)ia*8);
      float4 A = pa4[0], B = pa4[1];
      float av[8] = {A.x,A.y,A.z,A.w,B.x,B.y,B.z,B.w};
      #pragma unroll
      for (int j = 0; j < 8; j++){ mAx += av[j]*w[j].x; mAy += av[j]*w[j].y; }
      const float4* pb4 = (const float4*)(ea + (size_t)ib*8);
      A = pb4[0]; B = pb4[1];
      float bvv[8] = {A.x,A.y,A.z,A.w,B.x,B.y,B.z,B.w};
      #pragma unroll
      for (int j = 0; j < 8; j++){ mBx += bvv[j]*w[j].x; mBy += bvv[j]*w[j].y; }
    }
    float eA = leaky(mAx)*att2.x + leaky(mAy)*att2.y;
    float eB = leaky(mBx)*att2.x + leaky(mBy)*att2.y;
    #pragma unroll
    for (int off = 1; off <= 16; off <<= 1){
      eA += __shfl_xor(eA, off);
      eB += __shfl_xor(eB, off);
    }
    float pA = va ? __expf(eA) : 0.f;
    float pB = vb ? __expf(eB) : 0.f;
    ox += pA*vA.x + pB*vB.x;
    oy += pA*vA.y + pB*vB.y;
    s  += pA + pB;
  }
  // combine the two halves' partial sums
  ox += __shfl_xor(ox, 32);
  oy += __shfl_xor(oy, 32);
  s  += __shfl_xor(s, 32);
  if (half == 0){
    float2 bsv = ((const float2*)bs)[n*32 + l2];
    float inv = 1.f/(s + 1e-16f);
    float2 r;
    r.x = ox*inv + bsv.x;
    r.y = oy*inv + bsv.y;
    ((float2*)(is_sc ? sc : bbv))[n*32 + l2] = r;
  }
}

// ---------------- heads: chi (sc) | fusion + v_com + backbone heads (bb) ----------------
// grid: [0,1250) chi, [1250,2500) fusion+bb heads
__global__ __launch_bounds__(256) void k_heads(
    const float* __restrict__ sc, const float* __restrict__ bbv, const int* __restrict__ rid,
    const float* __restrict__ bnuW, const float* __restrict__ bnub,
    const float* __restrict__ bnug, const float* __restrict__ bnube,
    const float* __restrict__ afW, const float* __restrict__ afb,
    const float* __restrict__ afg, const float* __restrict__ afbe,
    const float* __restrict__ vcW1, const float* __restrict__ vcb1,
    const float* __restrict__ vcW2, const float* __restrict__ vcb2,
    const float* __restrict__ chiW, const float* __restrict__ chib,
    const float* __restrict__ adW1, const float* __restrict__ adW2,
    const float* __restrict__ bbhW1, const float* __restrict__ bbhb1,
    const float* __restrict__ phiW2, const float* __restrict__ psiW2,
    const float* __restrict__ xcaW2, const float* __restrict__ xcab2,
    const float* __restrict__ vcbW2, const float* __restrict__ vcbb2,
    float* __restrict__ out){
  __shared__ float sx[1024];
  __shared__ float sh[1024];
  __shared__ int srid[16];
  int b = blockIdx.x, t = threadIdx.x;
  int d = t & 63, r = t >> 6;
  if (b < 1250){
    int tile = b;
    for (int i = t; i < 1024; i += 256) sx[i] = sc[tile*1024 + i];
    if (t < 16) srid[t] = rid[tile*16 + t];
    __syncthreads();
    for (int i = 0; i < 4; i++){
      const float* W = chiW + i*4096;
      float acc[4] = {0,0,0,0};
      #pragma unroll 4
      for (int k = 0; k < 64; k++){
        float w = W[k*64+d];
        #pragma unroll
        for (int j = 0; j < 4; j++) acc[j] += sx[(r + 4*j)*64 + k] * w;
      }
      float bi = chib[i*64+d];
      #pragma unroll
      for (int j = 0; j < 4; j++){
        float mk = chi_mask(srid[r + 4*j], i);
        sh[(r + 4*j)*64 + d] = fmaxf(acc[j] + bi, 0.f) * mk;
      }
      __syncthreads();
      float a2[4] = {0,0,0,0};
      #pragma unroll 4
      for (int k = 0; k < 64; k++){
        float w = adW1[k*64+d];
        #pragma unroll
        for (int j = 0; j < 4; j++) a2[j] += sh[(r + 4*j)*64 + k] * w;
      }
      float w2 = adW2[d];
      #pragma unroll
      for (int j = 0; j < 4; j++){
        float p = wsum(fmaxf(a2[j], 0.f) * w2);
        if (d == 0) out[i*NN + tile*16 + r + 4*j] = p;
      }
      __syncthreads();
    }
  } else {
    int tile = b - 1250;
    for (int i = t; i < 1024; i += 256){ sx[i] = sc[tile*1024 + i]; sh[i] = bbv[tile*1024 + i]; }
    __syncthreads();
    float aU[4] = {0,0,0,0}, aV[4] = {0,0,0,0};
    #pragma unroll 4
    for (int k = 0; k < 64; k++){
      float wu = bnuW[k*64+d], wv = vcW1[k*64+d];
      #pragma unroll
      for (int j = 0; j < 4; j++){
        float xv = sx[(r + 4*j)*64 + k];
        aU[j] += xv*wu; aV[j] += xv*wv;
      }
    }
    float afwd = afW[d];
    float bnubd = bnub[d], bnugd = bnug[d], bnubed = bnube[d];
    float vcb1d = vcb1[d];
    float afbv = afb[0], afgv = afg[0], afbev = afbe[0];
    #pragma unroll
    for (int j = 0; j < 4; j++){
      int node = tile*16 + r + 4*j;
      float z = wsum(sx[(r + 4*j)*64 + d] * afwd);
      float attn = 1.f / (1.f + __expf(-((z + afbv)*BN_C*afgv + afbev)));
      float u = fmaxf((aU[j] + bnubd)*BN_C*bnugd + bnubed, 0.f);
      sh[(r + 4*j)*64 + d] += attn*u;
      float vh = fmaxf(aV[j] + vcb1d, 0.f);
      #pragma unroll
      for (int c = 0; c < 3; c++){
        float p = wsum(vh * vcW2[d*3+c]);
        if (d == 0) out[4*NN + node*3 + c] = p + vcb2[c];
      }
    }
    __syncthreads();
    for (int i = 0; i < 4; i++){
      const float* W = bbhW1 + i*4096;
      float acc[4] = {0,0,0,0};
      #pragma unroll 4
      for (int k = 0; k < 64; k++){
        float w = W[k*64+d];
        #pragma unroll
        for (int j = 0; j < 4; j++) acc[j] += sh[(r + 4*j)*64 + k] * w;
      }
      float bi = bbhb1[i*64+d];
      if (i < 2){
        float w2 = (i == 0) ? phiW2[d] : psiW2[d];
        #pragma unroll
        for (int j = 0; j < 4; j++){
          float p = wsum(fmaxf(acc[j] + bi, 0.f) * w2);
          if (d == 0) out[(7+i)*NN + tile*16 + r + 4*j] = p;
        }
      } else {
        const float* W2 = (i == 2) ? xcaW2 : vcbW2;
        const float* B2 = (i == 2) ? xcab2 : vcbb2;
        int off = (i == 2) ? 9*NN : 12*NN;
        #pragma unroll
        for (int j = 0; j < 4; j++){
          float h = fmaxf(acc[j] + bi, 0.f);
          #pragma unroll
          for (int c = 0; c < 3; c++){
            float p = wsum(h * W2[d*3+c]);
            if (d == 0) out[off + (tile*16 + r + 4*j)*3 + c] = p + B2[c];
          }
        }
      }
    }
  }
}

extern "C" __attribute__((visibility("default")))
void kernel_launch(void* const* d_in, const int* in_sizes, int n_in,
                   void* d_out, int out_size, void* d_ws, size_t ws_size,
                   hipStream_t stream) {
  (void)hipGetLastError();

  const float* Xsc   = (const float*)d_in[0];
  const float* Xbb   = (const float*)d_in[1];
  const float* attrs = (const float*)d_in[2];
  const int*  scE   = (const int*)d_in[3];
  const int*  bbE   = (const int*)d_in[4];
  const int*  rid   = (const int*)d_in[5];
  const float* scembW=(const float*)d_in[6];  const float* scembb=(const float*)d_in[7];
  const float* bbembW=(const float*)d_in[8];  const float* bbembb=(const float*)d_in[9];
  const float* resT  =(const float*)d_in[10];
  const float* rrW1  =(const float*)d_in[11]; const float* rrb1  =(const float*)d_in[12];
  const float* rrW2  =(const float*)d_in[13]; const float* rrb2  =(const float*)d_in[14];
  const float* scWl  =(const float*)d_in[15]; const float* scWr  =(const float*)d_in[16];
  const float* scWe  =(const float*)d_in[17]; const float* scAtt =(const float*)d_in[18];
  const float* scRes =(const float*)d_in[19]; const float* scBias=(const float*)d_in[20];
  const float* bbWl  =(const float*)d_in[21]; const float* bbWr  =(const float*)d_in[22];
  const float* bbAtt =(const float*)d_in[23]; const float* bbRes =(const float*)d_in[24];
  const float* bbBias=(const float*)d_in[25];
  const float* euW1  =(const float*)d_in[26]; const float* eub1  =(const float*)d_in[27];
  const float* eug   =(const float*)d_in[28]; const float* eube  =(const float*)d_in[29];
  const float* euW2  =(const float*)d_in[30]; const float* eub2  =(const float*)d_in[31];
  const float* bnuW  =(const float*)d_in[32]; const float* bnub  =(const float*)d_in[33];
  const float* bnug  =(const float*)d_in[34]; const float* bnube =(const float*)d_in[35];
  const float* afW   =(const float*)d_in[36]; const float* afb   =(const float*)d_in[37];
  const float* afg   =(const float*)d_in[38]; const float* afbe  =(const float*)d_in[39];
  const float* chiW  =(const float*)d_in[40]; const float* chib  =(const float*)d_in[41];
  const float* adW1  =(const float*)d_in[42]; const float* adW2  =(const float*)d_in[43];
  const float* vcW1  =(const float*)d_in[44]; const float* vcb1  =(const float*)d_in[45];
  const float* vcW2  =(const float*)d_in[46]; const float* vcb2  =(const float*)d_in[47];
  const float* bbhW1 =(const float*)d_in[48]; const float* bbhb1 =(const float*)d_in[49];
  const float* phiW2 =(const float*)d_in[50]; const float* psiW2 =(const float*)d_in[51];
  const float* xcaW2 =(const float*)d_in[52]; const float* xcab2 =(const float*)d_in[53];
  const float* vcbW2 =(const float*)d_in[54]; const float* vcbb2 =(const float*)d_in[55];
  float* out = (float*)d_out;

  size_t need = 1024 + (size_t)(8*NN*64 + NE*8)*4 + (size_t)(2*(NN+1) + 2*NN + 2*NE)*4;
  if (ws_size < need){
    k_mark<<<(NN+255)/256, 256, 0, stream>>>(out);
    return;
  }
  float* relTab = (float*)d_ws;
  float* f = (float*)((char*)d_ws + 1024);
  float* sc    = f; f += NN*64;
  float* bbuf  = f; f += NN*64;
  float* xl_sc = f; f += NN*64;
  float* xr_sc = f; f += NN*64;
  float* bs_sc = f; f += NN*64;
  float* xl_bb = f; f += NN*64;
  float* xr_bb = f; f += NN*64;
  float* bs_bb = f; f += NN*64;
  float* ea    = f; f += NE*8;
  int* ip = (int*)f;
  int* rp_sc  = ip; ip += NN+1;
  int* rp_bb  = ip; ip += NN+1;
  int* cnt_sc = ip; ip += NN;
  int* cnt_bb = ip; ip += NN;
  int* ps_sc  = ip; ip += NE;
  int* ps_bb  = ip; ip += NE;

  k_init<<<(2*NN + 255)/256, 256, 0, stream>>>(cnt_sc, 2*NN);
  k_pre<<<12500, 256, 0, stream>>>(Xsc, Xbb, scembW, scembb, bbembW, bbembb,
                                   scE, bbE, sc, bbuf, cnt_sc, cnt_bb);
  k_scan<<<3, 256, 0, stream>>>(cnt_sc, cnt_bb, rp_sc, rp_bb,
                                resT, rrW1, rrb1, rrW2, rrb2, relTab);
  k_scatter<<<2500, 256, 0, stream>>>(scE, bbE, rid, relTab, attrs,
                                      cnt_sc, cnt_bb, ps_sc, ps_bb, ea);
  for (int l = 0; l < NL; l++){
    k_layer1<<<3750, 256, 0, stream>>>(ea, l,
        euW1, eub1, eug, eube, euW2, eub2,
        sc, bbuf,
        scWl, scWr, scRes, scBias,
        bbWl, bbWr, bbRes, bbBias,
        xl_sc, xr_sc, bs_sc, xl_bb, xr_bb, bs_bb);
    k_agg<<<10000, 256, 0, stream>>>(sc, bbuf, l,
        xl_sc, xr_sc, bs_sc, xl_bb, xr_bb, bs_bb,
        rp_sc, ps_sc, rp_bb, ps_bb,
        ea, scWe, scAtt, bbAtt);
  }
  k_heads<<<2500, 256, 0, stream>>>(sc, bbuf, rid,
      bnuW, bnub, bnug, bnube, afW, afb, afg, afbe,
      vcW1, vcb1, vcW2, vcb2,
      chiW, chib, adW1, adW2, bbhW1, bbhb1,
      phiW2, psiW2, xcaW2, xcab2, vcbW2, vcbb2, out);
}

// Round 9
// 1343.304 us; speedup vs baseline: 1.6772x; 1.1185x over previous
//
#include <hip/hip_runtime.h>
#include <hip/hip_bf16.h>

#define NN 20000
#define NE 320000
#define NL 12
#define BN_C 0.9999950000374997f

// Inputs/outputs are float32 on the wire (proven R5: dtype probe + pass at 1.5e-5).

// packed chi-count per residue (LETTERS='ARNDCQEGHILKMFPSTWYV'), 3 bits each;
// reference mask is prefix-structured: mask[res][i] = (i < nchi[res]).
#define CHI_PACK ( (0ull<<0)|(4ull<<3)|(2ull<<6)|(2ull<<9)|(1ull<<12)|(3ull<<15)|(3ull<<18)|(0ull<<21) \
                 | (2ull<<24)|(2ull<<27)|(2ull<<30)|(4ull<<33)|(3ull<<36)|(2ull<<39)|(0ull<<42)|(1ull<<45) \
                 | (1ull<<48)|(2ull<<51)|(2ull<<54)|(1ull<<57) )
__device__ __forceinline__ float chi_mask(int res, int i){
  int nchi = (int)((CHI_PACK >> (3*res)) & 7ull);
  return (i < nchi) ? 1.f : 0.f;
}

__device__ __forceinline__ float wsum(float v){
  #pragma unroll
  for (int off = 32; off > 0; off >>= 1) v += __shfl_xor(v, off);
  return v;
}
__device__ __forceinline__ float leaky(float x){
  return fmaxf(x, 0.f) + 0.2f*fminf(x, 0.f);
}

// ---------------- zero counters ----------------
__global__ __launch_bounds__(256) void k_init(int* p, int n){
  int i = blockIdx.x*256 + threadIdx.x;
  if (i < n) p[i] = 0;
}

// ---------------- ws-too-small marker ----------------
__global__ __launch_bounds__(256) void k_mark(float* out){
  int i = blockIdx.x*256 + threadIdx.x;
  if (i < NN) out[i] = 9.0f;
}

// ---------------- embeddings + degree histograms ----------------
// grid: [0,5000) sc embed, [5000,10000) bb embed, [10000,11250) sc hist, [11250,12500) bb hist
__global__ __launch_bounds__(256) void k_pre(
    const float* __restrict__ Xsc, const float* __restrict__ Xbb,
    const float* __restrict__ Wsc, const float* __restrict__ bsc,
    const float* __restrict__ Wbb, const float* __restrict__ bbb,
    const int* __restrict__ scE, const int* __restrict__ bbE,
    float* __restrict__ sc, float* __restrict__ bbuf, int* cnt_sc, int* cnt_bb){
  int b = blockIdx.x, t = threadIdx.x;
  if (b < 5000){
    int tid = b*256 + t;
    int node = tid >> 6, d = tid & 63;
    float acc = bsc[d];
    #pragma unroll
    for (int k = 0; k < 21; k++) acc += Xsc[node*21+k] * Wsc[k*64+d];
    sc[tid] = fmaxf(acc, 0.f);
  } else if (b < 10000){
    int tid = (b-5000)*256 + t;
    int node = tid >> 6, d = tid & 63;
    float acc = bbb[d];
    #pragma unroll
    for (int k = 0; k < 12; k++) acc += Xbb[node*12+k] * Wbb[k*64+d];
    bbuf[tid] = fmaxf(acc, 0.f);
  } else if (b < 11250){
    int e = (b-10000)*256 + t;
    atomicAdd(&cnt_sc[scE[NE + e]], 1);
  } else {
    int e = (b-11250)*256 + t;
    atomicAdd(&cnt_bb[bbE[NE + e]], 1);
  }
}

// ---------------- scan (blocks 0,1) + rel-gate table (block 2) ----------------
__global__ __launch_bounds__(256) void k_scan(
    int* cnt_sc, int* cnt_bb, int* rp_sc, int* rp_bb,
    const float* __restrict__ resT, const float* __restrict__ rrW1,
    const float* __restrict__ rrb1, const float* __restrict__ rrW2,
    const float* __restrict__ rrb2, float* relTab){
  int t = threadIdx.x;
  if (blockIdx.x == 2){
    __shared__ float sRT[320], sW1[512], sB1[16], sW2[16];
    for (int i = t; i < 320; i += 256) sRT[i] = resT[i];
    for (int i = t; i < 512; i += 256) sW1[i] = rrW1[i];
    if (t < 16){ sB1[t] = rrb1[t]; sW2[t] = rrW2[t]; }
    __syncthreads();
    float b2v = rrb2[0];
    for (int p = t; p < 400; p += 256){
      int a = p / 20, c = p % 20;
      const float* ra = &sRT[a*16];
      const float* rc = &sRT[c*16];
      float z = b2v;
      #pragma unroll
      for (int j = 0; j < 16; j++){
        float h = sB1[j];
        #pragma unroll
        for (int i = 0; i < 16; i++) h += ra[i] * sW1[i*16+j];
        #pragma unroll
        for (int i = 0; i < 16; i++) h += rc[i] * sW1[(16+i)*16+j];
        z += fmaxf(h, 0.f) * sW2[j];
      }
      relTab[p] = 1.f / (1.f + __expf(-z));
    }
    return;
  }
  int* cnt = blockIdx.x ? cnt_bb : cnt_sc;
  int* rp  = blockIdx.x ? rp_bb  : rp_sc;
  __shared__ int s[256];
  const int CH = 79;
  int beg = t * CH;
  int sum = 0;
  for (int i = beg; i < beg + CH && i < NN; i++) sum += cnt[i];
  s[t] = sum; __syncthreads();
  for (int off = 1; off < 256; off <<= 1){
    int v = (t >= off) ? s[t-off] : 0;
    __syncthreads();
    s[t] += v;
    __syncthreads();
  }
  int run = (t == 0) ? 0 : s[t-1];
  for (int i = beg; i < beg + CH && i < NN; i++){
    int c = cnt[i];
    rp[i] = run;
    cnt[i] = run;      // cursor for scatter
    run += c;
  }
  if (t == 0) rp[NN] = NE;
}

// ---------------- scatter: perm_src + gated sorted edge attrs ----------------
__global__ __launch_bounds__(256) void k_scatter(
    const int* __restrict__ scE, const int* __restrict__ bbE, const int* __restrict__ rid,
    const float* __restrict__ relTab, const float* __restrict__ attrs,
    int* cur_sc, int* cur_bb, int* __restrict__ ps_sc, int* __restrict__ ps_bb,
    float* __restrict__ ea){
  int b = blockIdx.x, t = threadIdx.x;
  if (b < 1250){
    int e = b*256 + t;
    int s = scE[e], d = scE[NE + e];
    float rel = relTab[rid[s]*20 + rid[d]];
    float4 A = ((const float4*)attrs)[e*2];
    float4 B = ((const float4*)attrs)[e*2+1];
    A.x *= rel; A.y *= rel; A.z *= rel; A.w *= rel;
    B.x *= rel; B.y *= rel; B.z *= rel; B.w *= rel;
    int pos = atomicAdd(&cur_sc[d], 1);
    ps_sc[pos] = s;
    ((float4*)ea)[pos*2]   = A;
    ((float4*)ea)[pos*2+1] = B;
  } else {
    int e = (b-1250)*256 + t;
    int s = bbE[e], d = bbE[NE + e];
    int pos = atomicAdd(&cur_bb[d], 1);
    ps_bb[pos] = s;
  }
}

// ---------------- per-node matmuls ----------------
__device__ void node_mm(float* sx, const float* __restrict__ x,
                        const float* __restrict__ Wl, const float* __restrict__ Wr,
                        const float* __restrict__ Wres, const float* __restrict__ bias, int l,
                        float* __restrict__ xl, float* __restrict__ xr, float* __restrict__ base,
                        int tile){
  int t = threadIdx.x;
  for (int i = t; i < 1024; i += 256) sx[i] = x[tile*1024 + i];
  __syncthreads();
  int d = t & 63, r = t >> 6;
  int wo = l*4096 + d;
  float aL[4] = {0,0,0,0}, aR[4] = {0,0,0,0}, aB[4];
  float bv = bias[l*64 + d];
  #pragma unroll
  for (int j = 0; j < 4; j++) aB[j] = bv;
  #pragma unroll 4
  for (int k = 0; k < 64; k++){
    float wl = Wl[wo + k*64], wr = Wr[wo + k*64], ws = Wres[wo + k*64];
    #pragma unroll
    for (int j = 0; j < 4; j++){
      float xv = sx[(r + 4*j)*64 + k];
      aL[j] += xv*wl; aR[j] += xv*wr; aB[j] += xv*ws;
    }
  }
  int n0 = tile*16 + r;
  #pragma unroll
  for (int j = 0; j < 4; j++){
    int n = n0 + 4*j;
    xl[n*64+d] = aL[j]; xr[n*64+d] = aR[j]; base[n*64+d] = aB[j];
  }
}

// grid roles: [0,1250) edge update, [1250,2500) sc node mm, [2500,3750) bb node mm
__global__ __launch_bounds__(256) void k_layer1(
    float* __restrict__ ea, int l,
    const float* __restrict__ euW1, const float* __restrict__ eub1,
    const float* __restrict__ eug, const float* __restrict__ eube,
    const float* __restrict__ euW2, const float* __restrict__ eub2,
    const float* __restrict__ sc, const float* __restrict__ bbv,
    const float* __restrict__ scWl, const float* __restrict__ scWr,
    const float* __restrict__ scRes, const float* __restrict__ scBias,
    const float* __restrict__ bbWl, const float* __restrict__ bbWr,
    const float* __restrict__ bbRes, const float* __restrict__ bbBias,
    float* __restrict__ xl_sc, float* __restrict__ xr_sc, float* __restrict__ bs_sc,
    float* __restrict__ xl_bb, float* __restrict__ xr_bb, float* __restrict__ bs_bb){
  __shared__ float smem[1024];
  int b = blockIdx.x, t = threadIdx.x;
  if (b < 1250){
    float* sW1 = smem;        float* sB1 = smem+128; float* sG  = smem+144;
    float* sBe = smem+160;    float* sW2 = smem+176; float* sB2 = smem+304;
    for (int i = t; i < 128; i += 256){ sW1[i] = euW1[l*128+i]; sW2[i] = euW2[l*128+i]; }
    if (t < 16){ sB1[t] = eub1[l*16+t]; sG[t] = eug[l*16+t]; sBe[t] = eube[l*16+t]; }
    if (t < 8) sB2[t] = eub2[l*8+t];
    __syncthreads();
    int e = b*256 + t;
    float4 A = ((const float4*)ea)[e*2];
    float4 B = ((const float4*)ea)[e*2+1];
    float a[8] = {A.x,A.y,A.z,A.w,B.x,B.y,B.z,B.w};
    float h[16];
    #pragma unroll
    for (int j = 0; j < 16; j++){
      float v = sB1[j];
      #pragma unroll
      for (int i = 0; i < 8; i++) v += a[i] * sW1[i*16+j];
      h[j] = fmaxf(v*BN_C*sG[j] + sBe[j], 0.f);
    }
    #pragma unroll
    for (int i = 0; i < 8; i++){
      float v = sB2[i] + a[i];
      #pragma unroll
      for (int j = 0; j < 16; j++) v += h[j] * sW2[j*8+i];
      a[i] = v;
    }
    ((float4*)ea)[e*2]   = make_float4(a[0],a[1],a[2],a[3]);
    ((float4*)ea)[e*2+1] = make_float4(a[4],a[5],a[6],a[7]);
  } else if (b < 2500){
    node_mm(smem, sc, scWl, scWr, scRes, scBias, l, xl_sc, xr_sc, bs_sc, b-1250);
  } else {
    node_mm(smem, bbv, bbWl, bbWr, bbRes, bbBias, l, xl_bb, xr_bb, bs_bb, b-2500);
  }
}

// ---------------- GAT aggregation: half-wave per edge + gather prefetch ----------------
// Each 32-lane half-wave owns one edge; lane l2 holds dims {2*l2, 2*l2+1}.
// The random xl gather (the only high-latency load) is prefetched one
// iteration ahead; ps/ea are sequential (L2/prefetcher-friendly) and stay
// in-iteration to keep VGPR ~52 (8 waves/SIMD).
// grid: [0,5000) sc graph, [5000,10000) bb graph; 4 waves/block
__global__ __launch_bounds__(256) void k_agg(
    float* __restrict__ sc, float* __restrict__ bbv, int l,
    const float* __restrict__ xl_sc, const float* __restrict__ xr_sc, const float* __restrict__ bs_sc,
    const float* __restrict__ xl_bb, const float* __restrict__ xr_bb, const float* __restrict__ bs_bb,
    const int* __restrict__ rp_sc, const int* __restrict__ ps_sc,
    const int* __restrict__ rp_bb, const int* __restrict__ ps_bb,
    const float* __restrict__ ea, const float* __restrict__ We,
    const float* __restrict__ scAtt, const float* __restrict__ bbAtt){
  int b = blockIdx.x;
  int lane = threadIdx.x & 63, wid = threadIdx.x >> 6;
  int half = lane >> 5, l2 = lane & 31;
  bool is_sc = b < 5000;
  int n = (is_sc ? b : b - 5000)*4 + wid;
  const float* xl = is_sc ? xl_sc : xl_bb;
  const float* xr = is_sc ? xr_sc : xr_bb;
  const float* bs = is_sc ? bs_sc : bs_bb;
  const int* rp = is_sc ? rp_sc : rp_bb;
  const int* ps = is_sc ? ps_sc : ps_bb;
  const float2* xl2 = (const float2*)xl;
  float2 att2 = ((const float2*)((is_sc ? scAtt : bbAtt) + l*64))[l2];
  float2 w[8];
  if (is_sc){
    #pragma unroll
    for (int j = 0; j < 8; j++) w[j] = ((const float2*)(We + l*512 + j*64))[l2];
  }
  int beg = rp[n], end = rp[n+1];
  float2 xr2 = ((const float2*)xr)[n*32 + l2];
  float ox = 0.f, oy = 0.f, s = 0.f;
  if (beg < end){
    int last = end - 1;
    // prologue: first pair of gathers
    int ia = min(beg + half, last);
    int ib = min(beg + 2 + half, last);
    float2 vA = xl2[ps[ia]*32 + l2];
    float2 vB = xl2[ps[ib]*32 + l2];
    for (int eid = beg; eid < end; eid += 4){
      // prefetch next iteration's gathers (clamped; values unused past end)
      int nx = eid + 4;
      int ia_n = min(nx + half, last);
      int ib_n = min(nx + 2 + half, last);
      float2 vA_n = xl2[ps[ia_n]*32 + l2];
      float2 vB_n = xl2[ps[ib_n]*32 + l2];
      bool va = eid + half < end;
      bool vb = eid + 2 + half < end;
      float mAx = vA.x + xr2.x, mAy = vA.y + xr2.y;
      float mBx = vB.x + xr2.x, mBy = vB.y + xr2.y;
      if (is_sc){
        int cia = min(eid + half, last);
        int cib = min(eid + 2 + half, last);
        const float4* pa4 = (const float4*)(ea + (size_t)cia*8);
        float4 A = pa4[0], B = pa4[1];
        float av[8] = {A.x,A.y,A.z,A.w,B.x,B.y,B.z,B.w};
        #pragma unroll
        for (int j = 0; j < 8; j++){ mAx += av[j]*w[j].x; mAy += av[j]*w[j].y; }
        const float4* pb4 = (const float4*)(ea + (size_t)cib*8);
        A = pb4[0]; B = pb4[1];
        float bvv[8] = {A.x,A.y,A.z,A.w,B.x,B.y,B.z,B.w};
        #pragma unroll
        for (int j = 0; j < 8; j++){ mBx += bvv[j]*w[j].x; mBy += bvv[j]*w[j].y; }
      }
      float eA = leaky(mAx)*att2.x + leaky(mAy)*att2.y;
      float eB = leaky(mBx)*att2.x + leaky(mBy)*att2.y;
      #pragma unroll
      for (int off = 1; off <= 16; off <<= 1){
        eA += __shfl_xor(eA, off);
        eB += __shfl_xor(eB, off);
      }
      float pA = va ? __expf(eA) : 0.f;
      float pB = vb ? __expf(eB) : 0.f;
      ox += pA*vA.x + pB*vB.x;
      oy += pA*vA.y + pB*vB.y;
      s  += pA + pB;
      vA = vA_n; vB = vB_n;
    }
  }
  // combine the two halves' partial sums
  ox += __shfl_xor(ox, 32);
  oy += __shfl_xor(oy, 32);
  s  += __shfl_xor(s, 32);
  if (half == 0){
    float2 bsv = ((const float2*)bs)[n*32 + l2];
    float inv = 1.f/(s + 1e-16f);
    float2 r;
    r.x = ox*inv + bsv.x;
    r.y = oy*inv + bsv.y;
    ((float2*)(is_sc ? sc : bbv))[n*32 + l2] = r;
  }
}

// ---------------- heads: chi (sc) | fusion + v_com + backbone heads (bb) ----------------
// grid: [0,1250) chi, [1250,2500) fusion+bb heads
__global__ __launch_bounds__(256) void k_heads(
    const float* __restrict__ sc, const float* __restrict__ bbv, const int* __restrict__ rid,
    const float* __restrict__ bnuW, const float* __restrict__ bnub,
    const float* __restrict__ bnug, const float* __restrict__ bnube,
    const float* __restrict__ afW, const float* __restrict__ afb,
    const float* __restrict__ afg, const float* __restrict__ afbe,
    const float* __restrict__ vcW1, const float* __restrict__ vcb1,
    const float* __restrict__ vcW2, const float* __restrict__ vcb2,
    const float* __restrict__ chiW, const float* __restrict__ chib,
    const float* __restrict__ adW1, const float* __restrict__ adW2,
    const float* __restrict__ bbhW1, const float* __restrict__ bbhb1,
    const float* __restrict__ phiW2, const float* __restrict__ psiW2,
    const float* __restrict__ xcaW2, const float* __restrict__ xcab2,
    const float* __restrict__ vcbW2, const float* __restrict__ vcbb2,
    float* __restrict__ out){
  __shared__ float sx[1024];
  __shared__ float sh[1024];
  __shared__ int srid[16];
  int b = blockIdx.x, t = threadIdx.x;
  int d = t & 63, r = t >> 6;
  if (b < 1250){
    int tile = b;
    for (int i = t; i < 1024; i += 256) sx[i] = sc[tile*1024 + i];
    if (t < 16) srid[t] = rid[tile*16 + t];
    __syncthreads();
    for (int i = 0; i < 4; i++){
      const float* W = chiW + i*4096;
      float acc[4] = {0,0,0,0};
      #pragma unroll 4
      for (int k = 0; k < 64; k++){
        float w = W[k*64+d];
        #pragma unroll
        for (int j = 0; j < 4; j++) acc[j] += sx[(r + 4*j)*64 + k] * w;
      }
      float bi = chib[i*64+d];
      #pragma unroll
      for (int j = 0; j < 4; j++){
        float mk = chi_mask(srid[r + 4*j], i);
        sh[(r + 4*j)*64 + d] = fmaxf(acc[j] + bi, 0.f) * mk;
      }
      __syncthreads();
      float a2[4] = {0,0,0,0};
      #pragma unroll 4
      for (int k = 0; k < 64; k++){
        float w = adW1[k*64+d];
        #pragma unroll
        for (int j = 0; j < 4; j++) a2[j] += sh[(r + 4*j)*64 + k] * w;
      }
      float w2 = adW2[d];
      #pragma unroll
      for (int j = 0; j < 4; j++){
        float p = wsum(fmaxf(a2[j], 0.f) * w2);
        if (d == 0) out[i*NN + tile*16 + r + 4*j] = p;
      }
      __syncthreads();
    }
  } else {
    int tile = b - 1250;
    for (int i = t; i < 1024; i += 256){ sx[i] = sc[tile*1024 + i]; sh[i] = bbv[tile*1024 + i]; }
    __syncthreads();
    float aU[4] = {0,0,0,0}, aV[4] = {0,0,0,0};
    #pragma unroll 4
    for (int k = 0; k < 64; k++){
      float wu = bnuW[k*64+d], wv = vcW1[k*64+d];
      #pragma unroll
      for (int j = 0; j < 4; j++){
        float xv = sx[(r + 4*j)*64 + k];
        aU[j] += xv*wu; aV[j] += xv*wv;
      }
    }
    float afwd = afW[d];
    float bnubd = bnub[d], bnugd = bnug[d], bnubed = bnube[d];
    float vcb1d = vcb1[d];
    float afbv = afb[0], afgv = afg[0], afbev = afbe[0];
    #pragma unroll
    for (int j = 0; j < 4; j++){
      int node = tile*16 + r + 4*j;
      float z = wsum(sx[(r + 4*j)*64 + d] * afwd);
      float attn = 1.f / (1.f + __expf(-((z + afbv)*BN_C*afgv + afbev)));
      float u = fmaxf((aU[j] + bnubd)*BN_C*bnugd + bnubed, 0.f);
      sh[(r + 4*j)*64 + d] += attn*u;
      float vh = fmaxf(aV[j] + vcb1d, 0.f);
      #pragma unroll
      for (int c = 0; c < 3; c++){
        float p = wsum(vh * vcW2[d*3+c]);
        if (d == 0) out[4*NN + node*3 + c] = p + vcb2[c];
      }
    }
    __syncthreads();
    for (int i = 0; i < 4; i++){
      const float* W = bbhW1 + i*4096;
      float acc[4] = {0,0,0,0};
      #pragma unroll 4
      for (int k = 0; k < 64; k++){
        float w = W[k*64+d];
        #pragma unroll
        for (int j = 0; j < 4; j++) acc[j] += sh[(r + 4*j)*64 + k] * w;
      }
      float bi = bbhb1[i*64+d];
      if (i < 2){
        float w2 = (i == 0) ? phiW2[d] : psiW2[d];
        #pragma unroll
        for (int j = 0; j < 4; j++){
          float p = wsum(fmaxf(acc[j] + bi, 0.f) * w2);
          if (d == 0) out[(7+i)*NN + tile*16 + r + 4*j] = p;
        }
      } else {
        const float* W2 = (i == 2) ? xcaW2 : vcbW2;
        const float* B2 = (i == 2) ? xcab2 : vcbb2;
        int off = (i == 2) ? 9*NN : 12*NN;
        #pragma unroll
        for (int j = 0; j < 4; j++){
          float h = fmaxf(acc[j] + bi, 0.f);
          #pragma unroll
          for (int c = 0; c < 3; c++){
            float p = wsum(h * W2[d*3+c]);
            if (d == 0) out[off + (tile*16 + r + 4*j)*3 + c] = p + B2[c];
          }
        }
      }
    }
  }
}

extern "C" __attribute__((visibility("default")))
void kernel_launch(void* const* d_in, const int* in_sizes, int n_in,
                   void* d_out, int out_size, void* d_ws, size_t ws_size,
                   hipStream_t stream) {
  (void)hipGetLastError();

  const float* Xsc   = (const float*)d_in[0];
  const float* Xbb   = (const float*)d_in[1];
  const float* attrs = (const float*)d_in[2];
  const int*  scE   = (const int*)d_in[3];
  const int*  bbE   = (const int*)d_in[4];
  const int*  rid   = (const int*)d_in[5];
  const float* scembW=(const float*)d_in[6];  const float* scembb=(const float*)d_in[7];
  const float* bbembW=(const float*)d_in[8];  const float* bbembb=(const float*)d_in[9];
  const float* resT  =(const float*)d_in[10];
  const float* rrW1  =(const float*)d_in[11]; const float* rrb1  =(const float*)d_in[12];
  const float* rrW2  =(const float*)d_in[13]; const float* rrb2  =(const float*)d_in[14];
  const float* scWl  =(const float*)d_in[15]; const float* scWr  =(const float*)d_in[16];
  const float* scWe  =(const float*)d_in[17]; const float* scAtt =(const float*)d_in[18];
  const float* scRes =(const float*)d_in[19]; const float* scBias=(const float*)d_in[20];
  const float* bbWl  =(const float*)d_in[21]; const float* bbWr  =(const float*)d_in[22];
  const float* bbAtt =(const float*)d_in[23]; const float* bbRes =(const float*)d_in[24];
  const float* bbBias=(const float*)d_in[25];
  const float* euW1  =(const float*)d_in[26]; const float* eub1  =(const float*)d_in[27];
  const float* eug   =(const float*)d_in[28]; const float* eube  =(const float*)d_in[29];
  const float* euW2  =(const float*)d_in[30]; const float* eub2  =(const float*)d_in[31];
  const float* bnuW  =(const float*)d_in[32]; const float* bnub  =(const float*)d_in[33];
  const float* bnug  =(const float*)d_in[34]; const float* bnube =(const float*)d_in[35];
  const float* afW   =(const float*)d_in[36]; const float* afb   =(const float*)d_in[37];
  const float* afg   =(const float*)d_in[38]; const float* afbe  =(const float*)d_in[39];
  const float* chiW  =(const float*)d_in[40]; const float* chib  =(const float*)d_in[41];
  const float* adW1  =(const float*)d_in[42]; const float* adW2  =(const float*)d_in[43];
  const float* vcW1  =(const float*)d_in[44]; const float* vcb1  =(const float*)d_in[45];
  const float* vcW2  =(const float*)d_in[46]; const float* vcb2  =(const float*)d_in[47];
  const float* bbhW1 =(const float*)d_in[48]; const float* bbhb1 =(const float*)d_in[49];
  const float* phiW2 =(const float*)d_in[50]; const float* psiW2 =(const float*)d_in[51];
  const float* xcaW2 =(const float*)d_in[52]; const float* xcab2 =(const float*)d_in[53];
  const float* vcbW2 =(const float*)d_in[54]; const float* vcbb2 =(const float*)d_in[55];
  float* out = (float*)d_out;

  size_t need = 1024 + (size_t)(8*NN*64 + NE*8)*4 + (size_t)(2*(NN+1) + 2*NN + 2*NE)*4;
  if (ws_size < need){
    k_mark<<<(NN+255)/256, 256, 0, stream>>>(out);
    return;
  }
  float* relTab = (float*)d_ws;
  float* f = (float*)((char*)d_ws + 1024);
  float* sc    = f; f += NN*64;
  float* bbuf  = f; f += NN*64;
  float* xl_sc = f; f += NN*64;
  float* xr_sc = f; f += NN*64;
  float* bs_sc = f; f += NN*64;
  float* xl_bb = f; f += NN*64;
  float* xr_bb = f; f += NN*64;
  float* bs_bb = f; f += NN*64;
  float* ea    = f; f += NE*8;
  int* ip = (int*)f;
  int* rp_sc  = ip; ip += NN+1;
  int* rp_bb  = ip; ip += NN+1;
  int* cnt_sc = ip; ip += NN;
  int* cnt_bb = ip; ip += NN;
  int* ps_sc  = ip; ip += NE;
  int* ps_bb  = ip; ip += NE;

  k_init<<<(2*NN + 255)/256, 256, 0, stream>>>(cnt_sc, 2*NN);
  k_pre<<<12500, 256, 0, stream>>>(Xsc, Xbb, scembW, scembb, bbembW, bbembb,
                                   scE, bbE, sc, bbuf, cnt_sc, cnt_bb);
  k_scan<<<3, 256, 0, stream>>>(cnt_sc, cnt_bb, rp_sc, rp_bb,
                                resT, rrW1, rrb1, rrW2, rrb2, relTab);
  k_scatter<<<2500, 256, 0, stream>>>(scE, bbE, rid, relTab, attrs,
                                      cnt_sc, cnt_bb, ps_sc, ps_bb, ea);
  for (int l = 0; l < NL; l++){
    k_layer1<<<3750, 256, 0, stream>>>(ea, l,
        euW1, eub1, eug, eube, euW2, eub2,
        sc, bbuf,
        scWl, scWr, scRes, scBias,
        bbWl, bbWr, bbRes, bbBias,
        xl_sc, xr_sc, bs_sc, xl_bb, xr_bb, bs_bb);
    k_agg<<<10000, 256, 0, stream>>>(sc, bbuf, l,
        xl_sc, xr_sc, bs_sc, xl_bb, xr_bb, bs_bb,
        rp_sc, ps_sc, rp_bb, ps_bb,
        ea, scWe, scAtt, bbAtt);
  }
  k_heads<<<2500, 256, 0, stream>>>(sc, bbuf, rid,
      bnuW, bnub, bnug, bnube, afW, afb, afg, afbe,
      vcW1, vcb1, vcW2, vcb2,
      chiW, chib, adW1, adW2, bbhW1, bbhb1,
      phiW2, psiW2, xcaW2, xcab2, vcbW2, vcbb2, out);
}